// Round 9
// baseline (180.459 us; speedup 1.0000x reference)
//
#include <hip/hip_runtime.h>

// ---- constants -------------------------------------------------------------
#define BATCH 4
#define SEQ   1024
#define KENC  512
#define HDIM  1024
#define NHEAD 16
#define HD    64
#define LOG2E 1.44269504088896340736f

typedef __attribute__((ext_vector_type(8))) short bf16x8;
typedef __attribute__((ext_vector_type(4))) float f32x4;
typedef __attribute__((ext_vector_type(16))) float f32x16;
typedef __attribute__((ext_vector_type(4))) float f4v;
typedef __attribute__((ext_vector_type(4))) short s4v;

__device__ __forceinline__ short f2bf(float f) {
  unsigned u = __float_as_uint(f);
  u += 0x7fffu + ((u >> 16) & 1u);   // RNE
  return (short)(u >> 16);
}

__device__ __forceinline__ void gload_lds16(const void* g, void* l) {
  __builtin_amdgcn_global_load_lds(
      (const __attribute__((address_space(1))) void*)g,
      (__attribute__((address_space(3))) void*)l, 16, 0, 0);
}

#define MF(A, B, C) __builtin_amdgcn_mfma_f32_16x16x32_bf16((A), (B), (C), 0, 0, 0)

// ---- kernel 1: f32 -> bf16 cast (both activations in one launch) -----------
__global__ __launch_bounds__(256) void cast2(const float* __restrict__ sa,
                                             short* __restrict__ da, int n4a,
                                             const float* __restrict__ sb,
                                             short* __restrict__ db, int n4b) {
  int i = blockIdx.x * 256 + threadIdx.x;
  const float* s;
  short* d;
  int j;
  if (i < n4a) { s = sa; d = da; j = i; }
  else { j = i - n4a; if (j >= n4b) return; s = sb; d = db; }
  f4v v = ((const f4v*)s)[j];
  s4v o;
#pragma unroll
  for (int k = 0; k < 4; ++k) o[k] = f2bf(v[k]);
  ((s4v*)d)[j] = o;
}

// ---- kernel 2: weight cast + transpose: Wt[n][k] = W[k][n] -----------------
struct WtArgs { const float* W[6]; };

__global__ __launch_bounds__(256) void wt_cast(WtArgs a, short* __restrict__ wt) {
  int j = blockIdx.z;
  const float* W = a.W[j];
  short* dst = wt + (size_t)j * (HDIM * HDIM);
  int cb = blockIdx.x * 32, rb = blockIdx.y * 32;
  __shared__ float t[32][33];
  int tx = threadIdx.x & 31, ty = threadIdx.x >> 5;
#pragma unroll
  for (int rr = 0; rr < 4; ++rr)
    t[ty + rr * 8][tx] = W[(size_t)(rb + ty + rr * 8) * HDIM + cb + tx];
  __syncthreads();
#pragma unroll
  for (int rr = 0; rr < 4; ++rr)
    dst[(size_t)(cb + ty + rr * 8) * HDIM + rb + tx] = f2bf(t[tx][ty + rr * 8]);
}

// ---- kernel 3: projection GEMM, 128x128 tile, BK=32, quad-buffer -----------
// Best-known structure (round 5): single barrier per K-step, counted vmcnt(8),
// stage tile t+3 while computing t.  XCD-chunked 1-D grid (round 8, FETCH/2).
struct ProjArgs {
  const short* X[6];
  const short* Wt[6];
  const float* bias[6];
  short* out[6];
  int tshift[6];  // log2(tokens): 10 or 9
  int mode[6];    // 0 std, 1 transposed
  float scale[6]; // epilogue scale (0.125*log2e for q/kq)
};

__global__ __launch_bounds__(256) void proj_gemm(ProjArgs a) {
  int lid = blockIdx.x;
  int t = (lid & 7) * 160 + (lid >> 3);   // bijective XCD chunking (1280=8*160)
  int job, bx, by;
  if (t < 1024) { job = t >> 8; int r = t & 255; bx = r & 7; by = r >> 3; }
  else { int u = t - 1024; job = 4 + (u >> 7); int r = u & 127; bx = r & 7; by = r >> 3; }

  const short* X = a.X[job];
  const short* W = a.Wt[job];

  __shared__ __align__(16) char Lds[65536];   // 4 bufs x (A 8K | B 8K)

  int tid = threadIdx.x, lane = tid & 63, wave = tid >> 6;
  int wr = wave >> 1, wc = wave & 1;
  int l15 = lane & 15, g4 = lane >> 4;

  f32x4 acc[4][4];
#pragma unroll
  for (int m = 0; m < 4; ++m)
#pragma unroll
    for (int n = 0; n < 4; ++n)
#pragma unroll
      for (int r = 0; r < 4; ++r) acc[m][n][r] = 0.0f;

  int arow = by * 128, brow = bx * 128;
  const int crow = lane >> 2;
  const int sgrp = (lane & 3) ^ ((lane >> 2) & 3) ^ (lane >> 4);
  const int rsw = (lane & 3) ^ (l15 >> 2);

  const char* Xb = (const char*)X;
  const char* Wb = (const char*)W;
  const size_t sac0 = ((size_t)(arow + 32 * wave + crow) * HDIM + sgrp * 8) * 2;
  const size_t sac1 = sac0 + (size_t)16 * HDIM * 2;
  const size_t sbc0 = ((size_t)(brow + 32 * wave + crow) * HDIM + sgrp * 8) * 2;
  const size_t sbc1 = sbc0 + (size_t)16 * HDIM * 2;
  const int ldA0 = wave * 2048, ldA1 = ldA0 + 1024;
  const int ldB0 = 8192 + ldA0, ldB1 = ldB0 + 1024;

  const int aoff = wr * 4096 + l15 * 64 + ((g4 ^ rsw) << 4);
  const int boff = 8192 + wc * 4096 + l15 * 64 + ((g4 ^ rsw) << 4);

#define STG_AB(SBO, SKT)                                                 \
  do {                                                                   \
    gload_lds16(Xb + sac0 + (size_t)(SKT) * 64, Lds + (SBO) + ldA0);     \
    gload_lds16(Xb + sac1 + (size_t)(SKT) * 64, Lds + (SBO) + ldA1);     \
    gload_lds16(Wb + sbc0 + (size_t)(SKT) * 64, Lds + (SBO) + ldB0);     \
    gload_lds16(Wb + sbc1 + (size_t)(SKT) * 64, Lds + (SBO) + ldB1);     \
  } while (0)

  // prologue: stage tiles 0,1,2 -> bufs 0,1,2; wait tile 0 (8 newest left).
  STG_AB(0, 0);
  STG_AB(16384, 1);
  STG_AB(32768, 2);
  asm volatile("s_waitcnt vmcnt(8)" ::: "memory");
  __builtin_amdgcn_s_barrier();
  asm volatile("" ::: "memory");

#define STEP(BO, DO_STG, SBO, SKT, VMW, ENDBAR)                               \
  do {                                                                        \
    bf16x8 a0 = *(const bf16x8*)(Lds + (BO) + 0 * 1024 + aoff);               \
    bf16x8 a1 = *(const bf16x8*)(Lds + (BO) + 1 * 1024 + aoff);               \
    bf16x8 a2 = *(const bf16x8*)(Lds + (BO) + 2 * 1024 + aoff);               \
    bf16x8 a3 = *(const bf16x8*)(Lds + (BO) + 3 * 1024 + aoff);               \
    bf16x8 b0 = *(const bf16x8*)(Lds + (BO) + 0 * 1024 + boff);               \
    bf16x8 b1 = *(const bf16x8*)(Lds + (BO) + 1 * 1024 + boff);               \
    bf16x8 b2 = *(const bf16x8*)(Lds + (BO) + 2 * 1024 + boff);               \
    bf16x8 b3 = *(const bf16x8*)(Lds + (BO) + 3 * 1024 + boff);               \
    if (DO_STG) STG_AB(SBO, SKT);                                             \
    __builtin_amdgcn_s_setprio(1);                                            \
    acc[0][0] = MF(a0, b0, acc[0][0]);                                        \
    acc[0][1] = MF(a0, b1, acc[0][1]);                                        \
    acc[0][2] = MF(a0, b2, acc[0][2]);                                        \
    acc[0][3] = MF(a0, b3, acc[0][3]);                                        \
    acc[1][0] = MF(a1, b0, acc[1][0]);                                        \
    acc[1][1] = MF(a1, b1, acc[1][1]);                                        \
    acc[1][2] = MF(a1, b2, acc[1][2]);                                        \
    acc[1][3] = MF(a1, b3, acc[1][3]);                                        \
    acc[2][0] = MF(a2, b0, acc[2][0]);                                        \
    acc[2][1] = MF(a2, b1, acc[2][1]);                                        \
    acc[2][2] = MF(a2, b2, acc[2][2]);                                        \
    acc[2][3] = MF(a2, b3, acc[2][3]);                                        \
    acc[3][0] = MF(a3, b0, acc[3][0]);                                        \
    acc[3][1] = MF(a3, b1, acc[3][1]);                                        \
    acc[3][2] = MF(a3, b2, acc[3][2]);                                        \
    acc[3][3] = MF(a3, b3, acc[3][3]);                                        \
    __builtin_amdgcn_s_setprio(0);                                            \
    asm volatile(VMW ::: "memory");                                           \
    if (ENDBAR) {                                                             \
      __builtin_amdgcn_s_barrier();                                           \
      asm volatile("" ::: "memory");                                          \
    }                                                                         \
  } while (0)

#pragma unroll 1
  for (int tt = 0; tt < 29; ++tt) {
    int bo = (tt & 3) << 14;
    int sbo = ((tt + 3) & 3) << 14;
    STEP(bo, 1, sbo, tt + 3, "s_waitcnt vmcnt(8)", 1);
  }
  STEP((29 & 3) << 14, 0, 0, 0, "s_waitcnt vmcnt(4)", 1);
  STEP((30 & 3) << 14, 0, 0, 0, "s_waitcnt vmcnt(0)", 1);
  STEP((31 & 3) << 14, 0, 0, 0, "s_nop 0", 0);

#undef STEP
#undef STG_AB

  const float* bias = a.bias[job];
  short* out = a.out[job];
  int tshift = a.tshift[job], tmask = (1 << tshift) - 1, mode = a.mode[job];
  float scl = a.scale[job];
#pragma unroll
  for (int m = 0; m < 4; ++m) {
    int rowb = arow + wr * 64 + m * 16 + (g4 << 2);
#pragma unroll
    for (int n = 0; n < 4; ++n) {
      int col = brow + wc * 64 + n * 16 + l15;
      float bv = bias[col];
      int head = col >> 6, d = col & 63;
#pragma unroll
      for (int r = 0; r < 4; ++r) {
        int row = rowb + r;
        int bb = row >> tshift, tk = row & tmask;
        float val = (acc[m][n][r] + bv) * scl;
        size_t idx;
        if (mode == 0)
          idx = ((((size_t)bb * NHEAD + head) << tshift) + tk) * 64 + d;
        else
          idx = ((((size_t)bb * NHEAD + head) * 64 + d) << tshift) + tk;
        out[idx] = f2bf(val);
      }
    }
  }
}

// ---- kernel 4: swapped-QK^T 32x32 flash attention, V direct from L2 --------
// K staged in LDS (reused by all 4 waves); V fragments loaded straight from
// the pre-transposed vT/kvT in global (XCD-local L2), issued at tile top so
// the ~200-400cy L2 latency hides under QK^T + softmax.
__global__ __launch_bounds__(256, 2) void attn32(
    const short* __restrict__ qall, const short* __restrict__ kall,
    const short* __restrict__ vTall, const short* __restrict__ kqall,
    const short* __restrict__ kkall, const short* __restrict__ kvTall,
    const float* __restrict__ amask, const float* __restrict__ emask,
    float* __restrict__ out) {
  __shared__ char KT[2][8192];
  __shared__ float red[4][32];

  int lid = blockIdx.x;
  int id = (lid & 7) * 64 + (lid >> 3);   // all 8 q-blocks of a bh -> same XCD
  int bh = id >> 3, qb = id & 7;
  int b = bh >> 4, h = bh & 15;
  int lane = threadIdx.x & 63, wave = threadIdx.x >> 6;
  int l31 = lane & 31, hi = lane >> 5, x7 = l31 & 7;
  int qrow0 = qb * 128 + wave * 32;

  bf16x8 qcur[4];
  {
    const short* qp = qall + ((size_t)bh * SEQ + qrow0 + l31) * 64;
#pragma unroll
    for (int i = 0; i < 4; ++i)
      qcur[i] = *(const bf16x8*)(qp + i * 16 + hi * 8);
  }

  const char* kb0 = (const char*)(kall + (size_t)bh * SEQ * 64);
  const char* vb0 = (const char*)(vTall + (size_t)bh * 64 * SEQ);
  const char* kb1 = (const char*)(kkall + (size_t)bh * KENC * 64);
  const char* vb1 = (const char*)(kvTall + (size_t)bh * 64 * KENC);
  const float* mpc = amask + (size_t)b * SEQ;

  // stage one K tile (64 rows x 128B) into KT[pb], swizzled dest-read pair
  auto STAGE_K = [&](int pb, const char* kb, int kt) {
    int t0 = threadIdx.x;
#pragma unroll
    for (int c = 0; c < 2; ++c) {
      int idx = c * 256 + t0;
      int row = idx >> 3, phys = idx & 7;
      int lg = phys ^ (row & 7);
      gload_lds16(kb + ((size_t)(kt * 64 + row)) * 128 + lg * 16,
                  KT[pb] + idx * 16);
    }
  };

  STAGE_K(0, kb0, 0);

  f32x16 ctx0, ctx1, c10, c11;
#pragma unroll
  for (int r = 0; r < 16; ++r) { ctx0[r] = 0.f; ctx1[r] = 0.f; c10[r] = 0.f; c11[r] = 0.f; }
  float mr = -1e30f, lr = 0.f;

#pragma unroll 1
  for (int t = 0; t < 24; ++t) {
    int p = t & 1;
    __syncthreads();                      // K tile t ready (staged last iter)

    // ---- V prefetch for tile t: straight from global (L2) into regs -------
    int kt = (t >= 16) ? t - 16 : t;
    const char* vbc = (t >= 16) ? vb1 : vb0;
    size_t vstride = (size_t)((t >= 16) ? KENC : SEQ) * 2;
    bf16x8 v00, v01, v02, v03, v10, v11, v12, v13;
    {
      const char* vrow0 = vbc + (size_t)l31 * vstride + (size_t)kt * 128 + hi * 16;
      const char* vrow1 = vrow0 + 32 * vstride;
      v00 = *(const bf16x8*)(vrow0);
      v01 = *(const bf16x8*)(vrow0 + 32);
      v02 = *(const bf16x8*)(vrow0 + 64);
      v03 = *(const bf16x8*)(vrow0 + 96);
      v10 = *(const bf16x8*)(vrow1);
      v11 = *(const bf16x8*)(vrow1 + 32);
      v12 = *(const bf16x8*)(vrow1 + 64);
      v13 = *(const bf16x8*)(vrow1 + 96);
    }

    if (t < 23) {                         // stage next K tile
      int tn = t + 1;
      if (tn >= 16) STAGE_K(p ^ 1, kb1, tn - 16);
      else          STAGE_K(p ^ 1, kb0, tn);
    }
    if (t == 16) {                        // finalize self branch
      if (!hi) red[wave][l31] = lr;
      asm volatile("s_waitcnt lgkmcnt(0)" ::: "memory");
#pragma unroll
      for (int r2 = 0; r2 < 4; ++r2) {
        f4v lv = *(const f4v*)(&red[wave][r2 * 8 + 4 * hi]);
#pragma unroll
        for (int j2 = 0; j2 < 4; ++j2) {
          float li = __builtin_amdgcn_rcpf(lv[j2]);
          int r = r2 * 4 + j2;
          c10[r] = ctx0[r] * li;  ctx0[r] = 0.f;
          c11[r] = ctx1[r] * li;  ctx1[r] = 0.f;
        }
      }
      mr = -1e30f; lr = 0.f;
      const short* kqp = kqall + ((size_t)bh * SEQ + qrow0 + l31) * 64;
#pragma unroll
      for (int i = 0; i < 4; ++i)
        qcur[i] = *(const bf16x8*)(kqp + i * 16 + hi * 8);
      mpc = emask + (size_t)b * KENC;
    }
    const char* Kp = KT[p];

    // ---- QK^T (swapped): lane owns q=l31 row -------------------------------
    f32x16 s0, s1;
#pragma unroll
    for (int r = 0; r < 16; ++r) { s0[r] = 0.f; s1[r] = 0.f; }
    __builtin_amdgcn_s_setprio(1);
#pragma unroll
    for (int i = 0; i < 4; ++i) {
      bf16x8 kf = *(const bf16x8*)(Kp + (l31)*128 + (((2 * i + hi) ^ x7) << 4));
      s0 = __builtin_amdgcn_mfma_f32_32x32x16_bf16(kf, qcur[i], s0, 0, 0, 0);
    }
#pragma unroll
    for (int i = 0; i < 4; ++i) {
      bf16x8 kf = *(const bf16x8*)(Kp + (32 + l31) * 128 + (((2 * i + hi) ^ x7) << 4));
      s1 = __builtin_amdgcn_mfma_f32_32x32x16_bf16(kf, qcur[i], s1, 0, 0, 0);
    }
    __builtin_amdgcn_s_setprio(0);

    const float* mp = mpc + kt * 64;
#pragma unroll
    for (int r2 = 0; r2 < 4; ++r2) {
      f4v ma = *(const f4v*)(mp + r2 * 8 + 4 * hi);
      f4v mb = *(const f4v*)(mp + 32 + r2 * 8 + 4 * hi);
#pragma unroll
      for (int j2 = 0; j2 < 4; ++j2) {
        s0[r2 * 4 + j2] = fmaf(ma[j2], LOG2E, s0[r2 * 4 + j2]);
        s1[r2 * 4 + j2] = fmaf(mb[j2], LOG2E, s1[r2 * 4 + j2]);
      }
    }

    float mx = s0[0];
#pragma unroll
    for (int r = 1; r < 16; ++r) mx = fmaxf(mx, s0[r]);
#pragma unroll
    for (int r = 0; r < 16; ++r) mx = fmaxf(mx, s1[r]);
    mx = fmaxf(mx, __int_as_float(__shfl_xor(__float_as_int(mx), 32)));

    if (!__all(mx <= mr + 12.f)) {        // defer-max rescale (rare)
      float mn = fmaxf(mr, mx);
      float scl = __builtin_amdgcn_exp2f(mr - mn);
      mr = mn; lr *= scl;
      if (!hi) red[wave][l31] = scl;
      asm volatile("s_waitcnt lgkmcnt(0)" ::: "memory");
#pragma unroll
      for (int r2 = 0; r2 < 4; ++r2) {
        f4v sv = *(const f4v*)(&red[wave][r2 * 8 + 4 * hi]);
#pragma unroll
        for (int j2 = 0; j2 < 4; ++j2) {
          ctx0[r2 * 4 + j2] *= sv[j2];
          ctx1[r2 * 4 + j2] *= sv[j2];
        }
      }
    }

    float rs = 0.f;
#pragma unroll
    for (int r = 0; r < 16; ++r) { s0[r] = __builtin_amdgcn_exp2f(s0[r] - mr); rs += s0[r]; }
#pragma unroll
    for (int r = 0; r < 16; ++r) { s1[r] = __builtin_amdgcn_exp2f(s1[r] - mr); rs += s1[r]; }
    rs += __int_as_float(__shfl_xor(__float_as_int(rs), 32));
    lr += rs;

    // ---- P -> bf16 A-frags in-register; PV with register V -----------------
#pragma unroll
    for (int s = 0; s < 2; ++s) {
      const f32x16& sv = s ? s1 : s0;
      unsigned W[8];
#pragma unroll
      for (int r2 = 0; r2 < 4; ++r2) {
        asm("v_cvt_pk_bf16_f32 %0, %1, %2"
            : "=v"(W[r2 * 2]) : "v"(sv[r2 * 4 + 0]), "v"(sv[r2 * 4 + 1]));
        asm("v_cvt_pk_bf16_f32 %0, %1, %2"
            : "=v"(W[r2 * 2 + 1]) : "v"(sv[r2 * 4 + 2]), "v"(sv[r2 * 4 + 3]));
      }
#pragma unroll
      for (int jr = 0; jr < 2; ++jr) {
        unsigned sendA = hi ? W[(2 * jr) * 2]     : W[(2 * jr + 1) * 2];
        unsigned sendB = hi ? W[(2 * jr) * 2 + 1] : W[(2 * jr + 1) * 2 + 1];
        unsigned rA = (unsigned)__shfl_xor((int)sendA, 32);
        unsigned rB = (unsigned)__shfl_xor((int)sendB, 32);
        union { unsigned u[4]; bf16x8 v; } pa;
        if (!hi) { pa.u[0] = W[2 * jr * 2]; pa.u[1] = W[2 * jr * 2 + 1];
                   pa.u[2] = rA;            pa.u[3] = rB; }
        else     { pa.u[0] = rA;            pa.u[1] = rB;
                   pa.u[2] = W[(2 * jr + 1) * 2]; pa.u[3] = W[(2 * jr + 1) * 2 + 1]; }
        int j = s * 2 + jr;
        bf16x8 vf0 = (j == 0) ? v00 : (j == 1) ? v01 : (j == 2) ? v02 : v03;
        bf16x8 vf1 = (j == 0) ? v10 : (j == 1) ? v11 : (j == 2) ? v12 : v13;
        __builtin_amdgcn_s_setprio(1);
        ctx0 = __builtin_amdgcn_mfma_f32_32x32x16_bf16(pa.v, vf0, ctx0, 0, 0, 0);
        ctx1 = __builtin_amdgcn_mfma_f32_32x32x16_bf16(pa.v, vf1, ctx1, 0, 0, 0);
        __builtin_amdgcn_s_setprio(0);
      }
    }
  }

  if (!hi) red[wave][l31] = lr;
  asm volatile("s_waitcnt lgkmcnt(0)" ::: "memory");
  float* op = out + ((size_t)b * SEQ) * HDIM + h * 64 + l31;
#pragma unroll
  for (int r2 = 0; r2 < 4; ++r2) {
    f4v lv = *(const f4v*)(&red[wave][r2 * 8 + 4 * hi]);
#pragma unroll
    for (int j2 = 0; j2 < 4; ++j2) {
      float li = __builtin_amdgcn_rcpf(lv[j2]);
      int s = qrow0 + r2 * 8 + 4 * hi + j2;
      int r = r2 * 4 + j2;
      op[(size_t)s * HDIM]      = 0.5f * (c10[r] + ctx0[r] * li);
      op[(size_t)s * HDIM + 32] = 0.5f * (c11[r] + ctx1[r] * li);
    }
  }
}

// ---- host launcher ---------------------------------------------------------
extern "C" void kernel_launch(void* const* d_in, const int* in_sizes, int n_in,
                              void* d_out, int out_size, void* d_ws, size_t ws_size,
                              hipStream_t stream) {
  const float* hid = (const float*)d_in[0];
  const float* enc = (const float*)d_in[1];
  const float* amask = (const float*)d_in[2];
  const float* emask = (const float*)d_in[3];

  char* ws = (char*)d_ws;
  short* hbf = (short*)(ws);                        // 8 MB  [B*S,H] bf16
  short* ebf = (short*)(ws + (8u << 20));           // 4 MB  [B*K,H]
  short* wt = (short*)(ws + (12u << 20));           // 12 MB 6x [n][k]
  short* qo = (short*)(ws + (24u << 20));           // 8 MB  [B,NH,S,HD]
  short* ko = (short*)(ws + (32u << 20));           // 8 MB
  short* vT = (short*)(ws + (40u << 20));           // 8 MB  [B,NH,HD,S]
  short* kqo = (short*)(ws + (48u << 20));          // 8 MB
  short* kko = (short*)(ws + (56u << 20));          // 4 MB  [B,NH,K,HD]
  short* kvT = (short*)(ws + (60u << 20));          // 4 MB  [B,NH,HD,K]

  cast2<<<6144, 256, 0, stream>>>(hid, hbf, (BATCH * SEQ * HDIM) / 4,
                                  enc, ebf, (BATCH * KENC * HDIM) / 4);

  WtArgs wa;
  for (int j = 0; j < 6; ++j) wa.W[j] = (const float*)d_in[4 + 2 * j];
  wt_cast<<<dim3(32, 32, 6), 256, 0, stream>>>(wa, wt);

  ProjArgs pa;
  const short* Xs[6] = {hbf, hbf, hbf, hbf, ebf, ebf};
  short* outs[6] = {qo, ko, vT, kqo, kko, kvT};
  const int tsh[6] = {10, 10, 10, 10, 9, 9};
  const int md[6] = {0, 0, 1, 0, 0, 1};
  const float qscale = 0.125f * LOG2E;
  const float scl[6] = {qscale, 1.f, 1.f, qscale, 1.f, 1.f};
  for (int j = 0; j < 6; ++j) {
    pa.X[j] = Xs[j];
    pa.Wt[j] = wt + (size_t)j * (HDIM * HDIM);
    pa.bias[j] = (const float*)d_in[5 + 2 * j];
    pa.out[j] = outs[j];
    pa.tshift[j] = tsh[j];
    pa.mode[j] = md[j];
    pa.scale[j] = scl[j];
  }
  proj_gemm<<<1280, 256, 0, stream>>>(pa);

  attn32<<<512, 256, 0, stream>>>(qo, ko, vT, kqo, kko, kvT, amask, emask,
                                  (float*)d_out);
}

// Round 10
// 166.663 us; speedup vs baseline: 1.0828x; 1.0828x over previous
//
#include <hip/hip_runtime.h>

// ---- constants -------------------------------------------------------------
#define BATCH 4
#define SEQ   1024
#define KENC  512
#define HDIM  1024
#define NHEAD 16
#define HD    64
#define LOG2E 1.44269504088896340736f

typedef __attribute__((ext_vector_type(8))) short bf16x8;
typedef __attribute__((ext_vector_type(4))) float f32x4;
typedef __attribute__((ext_vector_type(16))) float f32x16;
typedef __attribute__((ext_vector_type(4))) float f4v;
typedef __attribute__((ext_vector_type(4))) short s4v;

__device__ __forceinline__ short f2bf(float f) {
  unsigned u = __float_as_uint(f);
  u += 0x7fffu + ((u >> 16) & 1u);   // RNE
  return (short)(u >> 16);
}

__device__ __forceinline__ void gload_lds16(const void* g, void* l) {
  __builtin_amdgcn_global_load_lds(
      (const __attribute__((address_space(1))) void*)g,
      (__attribute__((address_space(3))) void*)l, 16, 0, 0);
}

#define MF(A, B, C) __builtin_amdgcn_mfma_f32_16x16x32_bf16((A), (B), (C), 0, 0, 0)

// ---- kernel 1: f32 -> bf16 cast (both activations in one launch) -----------
__global__ __launch_bounds__(256) void cast2(const float* __restrict__ sa,
                                             short* __restrict__ da, int n4a,
                                             const float* __restrict__ sb,
                                             short* __restrict__ db, int n4b) {
  int i = blockIdx.x * 256 + threadIdx.x;
  const float* s;
  short* d;
  int j;
  if (i < n4a) { s = sa; d = da; j = i; }
  else { j = i - n4a; if (j >= n4b) return; s = sb; d = db; }
  f4v v = ((const f4v*)s)[j];
  s4v o;
#pragma unroll
  for (int k = 0; k < 4; ++k) o[k] = f2bf(v[k]);
  ((s4v*)d)[j] = o;
}

// ---- kernel 2: weight cast + transpose: Wt[n][k] = W[k][n] -----------------
struct WtArgs { const float* W[6]; };

__global__ __launch_bounds__(256) void wt_cast(WtArgs a, short* __restrict__ wt) {
  int j = blockIdx.z;
  const float* W = a.W[j];
  short* dst = wt + (size_t)j * (HDIM * HDIM);
  int cb = blockIdx.x * 32, rb = blockIdx.y * 32;
  __shared__ float t[32][33];
  int tx = threadIdx.x & 31, ty = threadIdx.x >> 5;
#pragma unroll
  for (int rr = 0; rr < 4; ++rr)
    t[ty + rr * 8][tx] = W[(size_t)(rb + ty + rr * 8) * HDIM + cb + tx];
  __syncthreads();
#pragma unroll
  for (int rr = 0; rr < 4; ++rr)
    dst[(size_t)(cb + ty + rr * 8) * HDIM + rb + tx] = f2bf(t[tx][ty + rr * 8]);
}

// ---- kernel 3: PAIR-FUSED projection GEMM ----------------------------------
// One block computes TWO output tiles (jobs 2p, 2p+1) over a SHARED A tile:
// per K-step: stage A once + B0 + B1 (6 gloads), 12 ds_read_b128, 32 MFMA.
// Triple-buffered 24KB bufs, counted vmcnt(6) (stage t+2 during t), single
// barrier per step. 640 blocks; default order keeps bx->XCD B-residency.
struct ProjArgs {
  const short* X[3];      // per pair
  const short* Wt[6];
  const float* bias[6];
  short* out[6];
  int tshift[6];  // log2(tokens): 10 or 9
  int mode[6];    // 0 std, 1 transposed
  float scale[6]; // epilogue scale (0.125*log2e for q/kq)
};

__global__ __launch_bounds__(256) void proj_pair(ProjArgs a) {
  int lid = blockIdx.x;
  int pair, bx, by;
  if (lid < 512) { pair = lid >> 8; int r = lid & 255; bx = r & 7; by = r >> 3; }
  else           { pair = 2; int r = lid - 512;        bx = r & 7; by = r >> 3; }

  const short* X = a.X[pair];
  const char* W0b = (const char*)a.Wt[pair * 2];
  const char* W1b = (const char*)a.Wt[pair * 2 + 1];

  __shared__ __align__(16) char Lds[3 * 24576];   // 72 KB: 3 bufs x (A|B0|B1)

  int tid = threadIdx.x, lane = tid & 63, wave = tid >> 6;
  int wr = wave >> 1, wc = wave & 1;
  int l15 = lane & 15, g4 = lane >> 4;

  f32x4 acc0[4][4], acc1[4][4];
#pragma unroll
  for (int m = 0; m < 4; ++m)
#pragma unroll
    for (int n = 0; n < 4; ++n)
#pragma unroll
      for (int r = 0; r < 4; ++r) { acc0[m][n][r] = 0.0f; acc1[m][n][r] = 0.0f; }

  int arow = by * 128, brow = bx * 128;
  const int crow = lane >> 2;
  const int sgrp = (lane & 3) ^ ((lane >> 2) & 3) ^ (lane >> 4);
  const int rsw = (lane & 3) ^ (l15 >> 2);

  const char* Xb = (const char*)X;
  const size_t sa0 = ((size_t)(arow + 32 * wave + crow) * HDIM + sgrp * 8) * 2;
  const size_t sa1 = sa0 + (size_t)16 * HDIM * 2;
  const size_t sb0 = ((size_t)(brow + 32 * wave + crow) * HDIM + sgrp * 8) * 2;
  const size_t sb1 = sb0 + (size_t)16 * HDIM * 2;
  const int ldA0 = wave * 2048, ldA1 = ldA0 + 1024;

  const int aoff = wr * 4096 + l15 * 64 + ((g4 ^ rsw) << 4);
  const int boff = wc * 4096 + l15 * 64 + ((g4 ^ rsw) << 4);

#define STG_A(SBO, SKT)                                                      \
  do {                                                                       \
    gload_lds16(Xb + sa0 + (size_t)(SKT) * 64, Lds + (SBO) + ldA0);          \
    gload_lds16(Xb + sa1 + (size_t)(SKT) * 64, Lds + (SBO) + ldA1);          \
  } while (0)
#define STG_B0(SBO, SKT)                                                     \
  do {                                                                       \
    gload_lds16(W0b + sb0 + (size_t)(SKT) * 64, Lds + (SBO) + 8192 + ldA0);  \
    gload_lds16(W0b + sb1 + (size_t)(SKT) * 64, Lds + (SBO) + 8192 + ldA1);  \
  } while (0)
#define STG_B1(SBO, SKT)                                                     \
  do {                                                                       \
    gload_lds16(W1b + sb0 + (size_t)(SKT) * 64, Lds + (SBO) + 16384 + ldA0); \
    gload_lds16(W1b + sb1 + (size_t)(SKT) * 64, Lds + (SBO) + 16384 + ldA1); \
  } while (0)

  // prologue: stage tiles 0 -> buf0, 1 -> buf1 (12 loads); wait tile 0.
  STG_A(0, 0);     STG_B0(0, 0);     STG_B1(0, 0);
  STG_A(24576, 1); STG_B0(24576, 1); STG_B1(24576, 1);
  asm volatile("s_waitcnt vmcnt(6)" ::: "memory");
  __builtin_amdgcn_s_barrier();
  asm volatile("" ::: "memory");

#define STEP(BO, DO_STG, SBO, SKT, VMW, ENDBAR)                               \
  do {                                                                        \
    bf16x8 a0 = *(const bf16x8*)(Lds + (BO) + 0 * 1024 + aoff);               \
    bf16x8 a1 = *(const bf16x8*)(Lds + (BO) + 1 * 1024 + aoff);               \
    bf16x8 a2 = *(const bf16x8*)(Lds + (BO) + 2 * 1024 + aoff);               \
    bf16x8 a3 = *(const bf16x8*)(Lds + (BO) + 3 * 1024 + aoff);               \
    bf16x8 p0 = *(const bf16x8*)(Lds + (BO) + 8192 + 0 * 1024 + boff);        \
    bf16x8 p1 = *(const bf16x8*)(Lds + (BO) + 8192 + 1 * 1024 + boff);        \
    bf16x8 p2 = *(const bf16x8*)(Lds + (BO) + 8192 + 2 * 1024 + boff);        \
    bf16x8 p3 = *(const bf16x8*)(Lds + (BO) + 8192 + 3 * 1024 + boff);        \
    bf16x8 q0 = *(const bf16x8*)(Lds + (BO) + 16384 + 0 * 1024 + boff);       \
    bf16x8 q1 = *(const bf16x8*)(Lds + (BO) + 16384 + 1 * 1024 + boff);       \
    bf16x8 q2 = *(const bf16x8*)(Lds + (BO) + 16384 + 2 * 1024 + boff);       \
    bf16x8 q3 = *(const bf16x8*)(Lds + (BO) + 16384 + 3 * 1024 + boff);       \
    if (DO_STG) { STG_A(SBO, SKT); STG_B0(SBO, SKT); }                        \
    __builtin_amdgcn_s_setprio(1);                                            \
    acc0[0][0] = MF(a0, p0, acc0[0][0]);                                      \
    acc0[0][1] = MF(a0, p1, acc0[0][1]);                                      \
    acc0[0][2] = MF(a0, p2, acc0[0][2]);                                      \
    acc0[0][3] = MF(a0, p3, acc0[0][3]);                                      \
    acc0[1][0] = MF(a1, p0, acc0[1][0]);                                      \
    acc0[1][1] = MF(a1, p1, acc0[1][1]);                                      \
    acc0[1][2] = MF(a1, p2, acc0[1][2]);                                      \
    acc0[1][3] = MF(a1, p3, acc0[1][3]);                                      \
    acc0[2][0] = MF(a2, p0, acc0[2][0]);                                      \
    acc0[2][1] = MF(a2, p1, acc0[2][1]);                                      \
    acc0[2][2] = MF(a2, p2, acc0[2][2]);                                      \
    acc0[2][3] = MF(a2, p3, acc0[2][3]);                                      \
    acc0[3][0] = MF(a3, p0, acc0[3][0]);                                      \
    acc0[3][1] = MF(a3, p1, acc0[3][1]);                                      \
    acc0[3][2] = MF(a3, p2, acc0[3][2]);                                      \
    acc0[3][3] = MF(a3, p3, acc0[3][3]);                                      \
    __builtin_amdgcn_s_setprio(0);                                            \
    if (DO_STG) STG_B1(SBO, SKT);                                             \
    __builtin_amdgcn_s_setprio(1);                                            \
    acc1[0][0] = MF(a0, q0, acc1[0][0]);                                      \
    acc1[0][1] = MF(a0, q1, acc1[0][1]);                                      \
    acc1[0][2] = MF(a0, q2, acc1[0][2]);                                      \
    acc1[0][3] = MF(a0, q3, acc1[0][3]);                                      \
    acc1[1][0] = MF(a1, q0, acc1[1][0]);                                      \
    acc1[1][1] = MF(a1, q1, acc1[1][1]);                                      \
    acc1[1][2] = MF(a1, q2, acc1[1][2]);                                      \
    acc1[1][3] = MF(a1, q3, acc1[1][3]);                                      \
    acc1[2][0] = MF(a2, q0, acc1[2][0]);                                      \
    acc1[2][1] = MF(a2, q1, acc1[2][1]);                                      \
    acc1[2][2] = MF(a2, q2, acc1[2][2]);                                      \
    acc1[2][3] = MF(a2, q3, acc1[2][3]);                                      \
    acc1[3][0] = MF(a3, q0, acc1[3][0]);                                      \
    acc1[3][1] = MF(a3, q1, acc1[3][1]);                                      \
    acc1[3][2] = MF(a3, q2, acc1[3][2]);                                      \
    acc1[3][3] = MF(a3, q3, acc1[3][3]);                                      \
    __builtin_amdgcn_s_setprio(0);                                            \
    asm volatile(VMW ::: "memory");                                           \
    if (ENDBAR) {                                                             \
      __builtin_amdgcn_s_barrier();                                           \
      asm volatile("" ::: "memory");                                          \
    }                                                                         \
  } while (0)

#pragma unroll 1
  for (int it = 0; it < 10; ++it) {
    int t0 = it * 3;
    STEP(0,     1, 49152, t0 + 2, "s_waitcnt vmcnt(6)", 1);
    STEP(24576, 1, 0,     t0 + 3, "s_waitcnt vmcnt(6)", 1);
    STEP(49152, 1, 24576, t0 + 4, "s_waitcnt vmcnt(6)", 1);
  }
  // t=30 (buf0): drain stage(31); t=31 (buf1): final
  STEP(0,     0, 0, 0, "s_waitcnt vmcnt(0)", 1);
  STEP(24576, 0, 0, 0, "s_nop 0", 0);

#undef STEP
#undef STG_A
#undef STG_B0
#undef STG_B1

#pragma unroll
  for (int jj = 0; jj < 2; ++jj) {
    int j = pair * 2 + jj;
    const float* bias = a.bias[j];
    short* out = a.out[j];
    int tshift = a.tshift[j], tmask = (1 << tshift) - 1, mode = a.mode[j];
    float scl = a.scale[j];
#pragma unroll
    for (int m = 0; m < 4; ++m) {
      int rowb = arow + wr * 64 + m * 16 + (g4 << 2);
#pragma unroll
      for (int n = 0; n < 4; ++n) {
        int col = brow + wc * 64 + n * 16 + l15;
        float bv = bias[col];
        int head = col >> 6, d = col & 63;
#pragma unroll
        for (int r = 0; r < 4; ++r) {
          int row = rowb + r;
          int bb = row >> tshift, tk = row & tmask;
          float v = jj ? acc1[m][n][r] : acc0[m][n][r];
          float val = (v + bv) * scl;
          size_t idx;
          if (mode == 0)
            idx = ((((size_t)bb * NHEAD + head) << tshift) + tk) * 64 + d;
          else
            idx = ((((size_t)bb * NHEAD + head) * 64 + d) << tshift) + tk;
          out[idx] = f2bf(val);
        }
      }
    }
  }
}

// ---- kernel 4: swapped-QK^T 32x32 flash attention (r7 proven version) ------
__global__ __launch_bounds__(256, 3) void attn32(
    const short* __restrict__ qall, const short* __restrict__ kall,
    const short* __restrict__ vTall, const short* __restrict__ kqall,
    const short* __restrict__ kkall, const short* __restrict__ kvTall,
    const float* __restrict__ amask, const float* __restrict__ emask,
    float* __restrict__ out) {
  __shared__ char KT[2][8192];
  __shared__ char VT[2][8192];
  __shared__ float red[4][32];

  int lid = blockIdx.x;
  int id = (lid & 7) * 64 + (lid >> 3);
  int bh = id >> 3, qb = id & 7;
  int b = bh >> 4, h = bh & 15;
  int lane = threadIdx.x & 63, wave = threadIdx.x >> 6;
  int l31 = lane & 31, hi = lane >> 5, x7 = l31 & 7;
  int qrow0 = qb * 128 + wave * 32;

  bf16x8 qcur[4];
  {
    const short* qp = qall + ((size_t)bh * SEQ + qrow0 + l31) * 64;
#pragma unroll
    for (int i = 0; i < 4; ++i)
      qcur[i] = *(const bf16x8*)(qp + i * 16 + hi * 8);
  }

  const char* kb0 = (const char*)(kall + (size_t)bh * SEQ * 64);
  const char* vb0 = (const char*)(vTall + (size_t)bh * 64 * SEQ);
  const char* kb1 = (const char*)(kkall + (size_t)bh * KENC * 64);
  const char* vb1 = (const char*)(kvTall + (size_t)bh * 64 * KENC);
  const float* mpc = amask + (size_t)b * SEQ;

  auto STAGE = [&](int pb, const char* kb, const char* vb, size_t vrowb, int kt) {
    int t0 = threadIdx.x;
#pragma unroll
    for (int c = 0; c < 2; ++c) {
      int idx = c * 256 + t0;
      int row = idx >> 3, phys = idx & 7;
      int lg = phys ^ (row & 7);
      gload_lds16(kb + ((size_t)(kt * 64 + row)) * 128 + lg * 16,
                  KT[pb] + idx * 16);
      gload_lds16(vb + (size_t)row * vrowb + (size_t)kt * 128 + lg * 16,
                  VT[pb] + idx * 16);
    }
  };

  STAGE(0, kb0, vb0, SEQ * 2, 0);

  f32x16 ctx0, ctx1, c10, c11;
#pragma unroll
  for (int r = 0; r < 16; ++r) { ctx0[r] = 0.f; ctx1[r] = 0.f; c10[r] = 0.f; c11[r] = 0.f; }
  float mr = -1e30f, lr = 0.f;

#pragma unroll 1
  for (int t = 0; t < 24; ++t) {
    int p = t & 1;
    __syncthreads();
    if (t < 23) {
      int tn = t + 1;
      if (tn >= 16) STAGE(p ^ 1, kb1, vb1, KENC * 2, tn - 16);
      else          STAGE(p ^ 1, kb0, vb0, SEQ * 2, tn);
    }
    if (t == 16) {
      if (!hi) red[wave][l31] = lr;
      asm volatile("s_waitcnt lgkmcnt(0)" ::: "memory");
#pragma unroll
      for (int r2 = 0; r2 < 4; ++r2) {
        f4v lv = *(const f4v*)(&red[wave][r2 * 8 + 4 * hi]);
#pragma unroll
        for (int j2 = 0; j2 < 4; ++j2) {
          float li = __builtin_amdgcn_rcpf(lv[j2]);
          int r = r2 * 4 + j2;
          c10[r] = ctx0[r] * li;  ctx0[r] = 0.f;
          c11[r] = ctx1[r] * li;  ctx1[r] = 0.f;
        }
      }
      mr = -1e30f; lr = 0.f;
      const short* kqp = kqall + ((size_t)bh * SEQ + qrow0 + l31) * 64;
#pragma unroll
      for (int i = 0; i < 4; ++i)
        qcur[i] = *(const bf16x8*)(kqp + i * 16 + hi * 8);
      mpc = emask + (size_t)b * KENC;
    }
    int kt = (t >= 16) ? t - 16 : t;
    const char* Kp = KT[p];
    const char* Vp = VT[p];

    f32x16 s0, s1;
#pragma unroll
    for (int r = 0; r < 16; ++r) { s0[r] = 0.f; s1[r] = 0.f; }
    __builtin_amdgcn_s_setprio(1);
#pragma unroll
    for (int i = 0; i < 4; ++i) {
      bf16x8 kf = *(const bf16x8*)(Kp + (l31)*128 + (((2 * i + hi) ^ x7) << 4));
      s0 = __builtin_amdgcn_mfma_f32_32x32x16_bf16(kf, qcur[i], s0, 0, 0, 0);
    }
#pragma unroll
    for (int i = 0; i < 4; ++i) {
      bf16x8 kf = *(const bf16x8*)(Kp + (32 + l31) * 128 + (((2 * i + hi) ^ x7) << 4));
      s1 = __builtin_amdgcn_mfma_f32_32x32x16_bf16(kf, qcur[i], s1, 0, 0, 0);
    }
    __builtin_amdgcn_s_setprio(0);

    const float* mp = mpc + kt * 64;
#pragma unroll
    for (int r2 = 0; r2 < 4; ++r2) {
      f4v ma = *(const f4v*)(mp + r2 * 8 + 4 * hi);
      f4v mb = *(const f4v*)(mp + 32 + r2 * 8 + 4 * hi);
#pragma unroll
      for (int j2 = 0; j2 < 4; ++j2) {
        s0[r2 * 4 + j2] = fmaf(ma[j2], LOG2E, s0[r2 * 4 + j2]);
        s1[r2 * 4 + j2] = fmaf(mb[j2], LOG2E, s1[r2 * 4 + j2]);
      }
    }

    float mx = s0[0];
#pragma unroll
    for (int r = 1; r < 16; ++r) mx = fmaxf(mx, s0[r]);
#pragma unroll
    for (int r = 0; r < 16; ++r) mx = fmaxf(mx, s1[r]);
    mx = fmaxf(mx, __int_as_float(__shfl_xor(__float_as_int(mx), 32)));

    if (!__all(mx <= mr + 12.f)) {
      float mn = fmaxf(mr, mx);
      float scl = __builtin_amdgcn_exp2f(mr - mn);
      mr = mn; lr *= scl;
      if (!hi) red[wave][l31] = scl;
      asm volatile("s_waitcnt lgkmcnt(0)" ::: "memory");
#pragma unroll
      for (int r2 = 0; r2 < 4; ++r2) {
        f4v sv = *(const f4v*)(&red[wave][r2 * 8 + 4 * hi]);
#pragma unroll
        for (int j2 = 0; j2 < 4; ++j2) {
          ctx0[r2 * 4 + j2] *= sv[j2];
          ctx1[r2 * 4 + j2] *= sv[j2];
        }
      }
    }

    float rs = 0.f;
#pragma unroll
    for (int r = 0; r < 16; ++r) { s0[r] = __builtin_amdgcn_exp2f(s0[r] - mr); rs += s0[r]; }
#pragma unroll
    for (int r = 0; r < 16; ++r) { s1[r] = __builtin_amdgcn_exp2f(s1[r] - mr); rs += s1[r]; }
    rs += __int_as_float(__shfl_xor(__float_as_int(rs), 32));
    lr += rs;

#pragma unroll
    for (int s = 0; s < 2; ++s) {
      const f32x16& sv = s ? s1 : s0;
      unsigned W[8];
#pragma unroll
      for (int r2 = 0; r2 < 4; ++r2) {
        asm("v_cvt_pk_bf16_f32 %0, %1, %2"
            : "=v"(W[r2 * 2]) : "v"(sv[r2 * 4 + 0]), "v"(sv[r2 * 4 + 1]));
        asm("v_cvt_pk_bf16_f32 %0, %1, %2"
            : "=v"(W[r2 * 2 + 1]) : "v"(sv[r2 * 4 + 2]), "v"(sv[r2 * 4 + 3]));
      }
#pragma unroll
      for (int jr = 0; jr < 2; ++jr) {
        unsigned sendA = hi ? W[(2 * jr) * 2]     : W[(2 * jr + 1) * 2];
        unsigned sendB = hi ? W[(2 * jr) * 2 + 1] : W[(2 * jr + 1) * 2 + 1];
        unsigned rA = (unsigned)__shfl_xor((int)sendA, 32);
        unsigned rB = (unsigned)__shfl_xor((int)sendB, 32);
        union { unsigned u[4]; bf16x8 v; } pa;
        if (!hi) { pa.u[0] = W[2 * jr * 2]; pa.u[1] = W[2 * jr * 2 + 1];
                   pa.u[2] = rA;            pa.u[3] = rB; }
        else     { pa.u[0] = rA;            pa.u[1] = rB;
                   pa.u[2] = W[(2 * jr + 1) * 2]; pa.u[3] = W[(2 * jr + 1) * 2 + 1]; }
        int j = s * 2 + jr;
        __builtin_amdgcn_s_setprio(1);
        bf16x8 vf0 = *(const bf16x8*)(Vp + (l31)*128 + (((2 * j + hi) ^ x7) << 4));
        ctx0 = __builtin_amdgcn_mfma_f32_32x32x16_bf16(pa.v, vf0, ctx0, 0, 0, 0);
        bf16x8 vf1 = *(const bf16x8*)(Vp + (32 + l31) * 128 + (((2 * j + hi) ^ x7) << 4));
        ctx1 = __builtin_amdgcn_mfma_f32_32x32x16_bf16(pa.v, vf1, ctx1, 0, 0, 0);
        __builtin_amdgcn_s_setprio(0);
      }
    }
  }

  if (!hi) red[wave][l31] = lr;
  asm volatile("s_waitcnt lgkmcnt(0)" ::: "memory");
  float* op = out + ((size_t)b * SEQ) * HDIM + h * 64 + l31;
#pragma unroll
  for (int r2 = 0; r2 < 4; ++r2) {
    f4v lv = *(const f4v*)(&red[wave][r2 * 8 + 4 * hi]);
#pragma unroll
    for (int j2 = 0; j2 < 4; ++j2) {
      float li = __builtin_amdgcn_rcpf(lv[j2]);
      int s = qrow0 + r2 * 8 + 4 * hi + j2;
      int r = r2 * 4 + j2;
      op[(size_t)s * HDIM]      = 0.5f * (c10[r] + ctx0[r] * li);
      op[(size_t)s * HDIM + 32] = 0.5f * (c11[r] + ctx1[r] * li);
    }
  }
}

// ---- host launcher ---------------------------------------------------------
extern "C" void kernel_launch(void* const* d_in, const int* in_sizes, int n_in,
                              void* d_out, int out_size, void* d_ws, size_t ws_size,
                              hipStream_t stream) {
  const float* hid = (const float*)d_in[0];
  const float* enc = (const float*)d_in[1];
  const float* amask = (const float*)d_in[2];
  const float* emask = (const float*)d_in[3];

  char* ws = (char*)d_ws;
  short* hbf = (short*)(ws);                        // 8 MB  [B*S,H] bf16
  short* ebf = (short*)(ws + (8u << 20));           // 4 MB  [B*K,H]
  short* wt = (short*)(ws + (12u << 20));           // 12 MB 6x [n][k]
  short* qo = (short*)(ws + (24u << 20));           // 8 MB  [B,NH,S,HD]
  short* ko = (short*)(ws + (32u << 20));           // 8 MB
  short* vT = (short*)(ws + (40u << 20));           // 8 MB  [B,NH,HD,S]
  short* kqo = (short*)(ws + (48u << 20));          // 8 MB
  short* kko = (short*)(ws + (56u << 20));          // 4 MB  [B,NH,K,HD]
  short* kvT = (short*)(ws + (60u << 20));          // 4 MB  [B,NH,HD,K]

  cast2<<<6144, 256, 0, stream>>>(hid, hbf, (BATCH * SEQ * HDIM) / 4,
                                  enc, ebf, (BATCH * KENC * HDIM) / 4);

  WtArgs wa;
  for (int j = 0; j < 6; ++j) wa.W[j] = (const float*)d_in[4 + 2 * j];
  wt_cast<<<dim3(32, 32, 6), 256, 0, stream>>>(wa, wt);

  ProjArgs pa;
  pa.X[0] = hbf; pa.X[1] = hbf; pa.X[2] = ebf;
  short* outs[6] = {qo, ko, vT, kqo, kko, kvT};
  const int tsh[6] = {10, 10, 10, 10, 9, 9};
  const int md[6] = {0, 0, 1, 0, 0, 1};
  const float qscale = 0.125f * LOG2E;
  const float scl[6] = {qscale, 1.f, 1.f, qscale, 1.f, 1.f};
  for (int j = 0; j < 6; ++j) {
    pa.Wt[j] = wt + (size_t)j * (HDIM * HDIM);
    pa.bias[j] = (const float*)d_in[5 + 2 * j];
    pa.out[j] = outs[j];
    pa.tshift[j] = tsh[j];
    pa.mode[j] = md[j];
    pa.scale[j] = scl[j];
  }
  // job order note: pair0={q,k}, pair1={v,kq}, pair2={kk,kv}
  proj_pair<<<640, 256, 0, stream>>>(pa);

  attn32<<<512, 256, 0, stream>>>(qo, ko, vT, kqo, kko, kvT, amask, emask,
                                  (float*)d_out);
}

// Round 11
// 152.879 us; speedup vs baseline: 1.1804x; 1.0902x over previous
//
#include <hip/hip_runtime.h>

// ---- constants -------------------------------------------------------------
#define BATCH 4
#define SEQ   1024
#define KENC  512
#define HDIM  1024
#define NHEAD 16
#define HD    64
#define LOG2E 1.44269504088896340736f

typedef __attribute__((ext_vector_type(8))) short bf16x8;
typedef __attribute__((ext_vector_type(4))) float f32x4;
typedef __attribute__((ext_vector_type(16))) float f32x16;
typedef __attribute__((ext_vector_type(4))) float f4v;
typedef __attribute__((ext_vector_type(4))) short s4v;

__device__ __forceinline__ short f2bf(float f) {
  unsigned u = __float_as_uint(f);
  u += 0x7fffu + ((u >> 16) & 1u);   // RNE
  return (short)(u >> 16);
}

__device__ __forceinline__ void gload_lds16(const void* g, void* l) {
  __builtin_amdgcn_global_load_lds(
      (const __attribute__((address_space(1))) void*)g,
      (__attribute__((address_space(3))) void*)l, 16, 0, 0);
}

#define MF(A, B, C) __builtin_amdgcn_mfma_f32_16x16x32_bf16((A), (B), (C), 0, 0, 0)

// ---- kernel 1: fused prep — weight cast+transpose AND activation casts -----
struct PrepArgs { const float* W[6]; };

__global__ __launch_bounds__(256) void prep(PrepArgs a, short* __restrict__ wt,
                                            const float* __restrict__ hid,
                                            short* __restrict__ hbf, int n4h,
                                            const float* __restrict__ enc,
                                            short* __restrict__ ebf, int n4e) {
  __shared__ float t[32][33];
  int blk = blockIdx.x;
  if (blk < 6144) {
    // weight transpose: 1024 blocks per W (32x32 tiles of 32x32)
    int j = blk >> 10;
    int r = blk & 1023;
    int cb = (r & 31) * 32, rb = (r >> 5) * 32;
    const float* W = a.W[j];
    short* dst = wt + (size_t)j * (HDIM * HDIM);
    int tx = threadIdx.x & 31, ty = threadIdx.x >> 5;
#pragma unroll
    for (int rr = 0; rr < 4; ++rr)
      t[ty + rr * 8][tx] = W[(size_t)(rb + ty + rr * 8) * HDIM + cb + tx];
    __syncthreads();
#pragma unroll
    for (int rr = 0; rr < 4; ++rr)
      dst[(size_t)(cb + ty + rr * 8) * HDIM + rb + tx] = f2bf(t[tx][ty + rr * 8]);
  } else {
    int i = (blk - 6144) * 256 + threadIdx.x;
    const float* s;
    short* d;
    int j;
    if (i < n4h) { s = hid; d = hbf; j = i; }
    else { j = i - n4h; if (j >= n4e) return; s = enc; d = ebf; }
    f4v v = ((const f4v*)s)[j];
    s4v o;
#pragma unroll
    for (int k = 0; k < 4; ++k) o[k] = f2bf(v[k]);
    ((s4v*)d)[j] = o;
  }
}

// ---- kernel 3: projection GEMM, 128x128 tile, BK=32, quad-buffer -----------
// BEST-KNOWN (round 5): single barrier per K-step, counted vmcnt(8), stage
// tile t+3 while computing t.  3-D grid dim3(8,32,6): one bx-panel per
// dispatch wave keeps each W panel L2-resident (1-D XCD chunking was -15us).
struct ProjArgs {
  const short* X[6];
  const short* Wt[6];
  const float* bias[6];
  short* out[6];
  int M[6];
  int tshift[6];  // log2(tokens): 10 or 9
  int mode[6];    // 0 std, 1 transposed
  float scale[6]; // epilogue scale (0.125*log2e for q/kq)
};

__global__ __launch_bounds__(256) void proj_gemm(ProjArgs a) {
  int job = blockIdx.z;
  int M = a.M[job];
  int by = blockIdx.y;
  if (by * 128 >= M) return;
  int bx = blockIdx.x;
  const short* X = a.X[job];
  const short* W = a.Wt[job];

  __shared__ __align__(16) char Lds[65536];   // 4 bufs x (A 8K | B 8K)

  int tid = threadIdx.x, lane = tid & 63, wave = tid >> 6;
  int wr = wave >> 1, wc = wave & 1;
  int l15 = lane & 15, g4 = lane >> 4;

  f32x4 acc[4][4];
#pragma unroll
  for (int m = 0; m < 4; ++m)
#pragma unroll
    for (int n = 0; n < 4; ++n)
#pragma unroll
      for (int r = 0; r < 4; ++r) acc[m][n][r] = 0.0f;

  int arow = by * 128, brow = bx * 128;
  const int crow = lane >> 2;
  const int sgrp = (lane & 3) ^ ((lane >> 2) & 3) ^ (lane >> 4);
  const int rsw = (lane & 3) ^ (l15 >> 2);

  const char* Xb = (const char*)X;
  const char* Wb = (const char*)W;
  const size_t sac0 = ((size_t)(arow + 32 * wave + crow) * HDIM + sgrp * 8) * 2;
  const size_t sac1 = sac0 + (size_t)16 * HDIM * 2;
  const size_t sbc0 = ((size_t)(brow + 32 * wave + crow) * HDIM + sgrp * 8) * 2;
  const size_t sbc1 = sbc0 + (size_t)16 * HDIM * 2;
  const int ldA0 = wave * 2048, ldA1 = ldA0 + 1024;
  const int ldB0 = 8192 + ldA0, ldB1 = ldB0 + 1024;

  const int aoff = wr * 4096 + l15 * 64 + ((g4 ^ rsw) << 4);
  const int boff = 8192 + wc * 4096 + l15 * 64 + ((g4 ^ rsw) << 4);

#define STG_AB(SBO, SKT)                                                 \
  do {                                                                   \
    gload_lds16(Xb + sac0 + (size_t)(SKT) * 64, Lds + (SBO) + ldA0);     \
    gload_lds16(Xb + sac1 + (size_t)(SKT) * 64, Lds + (SBO) + ldA1);     \
    gload_lds16(Wb + sbc0 + (size_t)(SKT) * 64, Lds + (SBO) + ldB0);     \
    gload_lds16(Wb + sbc1 + (size_t)(SKT) * 64, Lds + (SBO) + ldB1);     \
  } while (0)

  STG_AB(0, 0);
  STG_AB(16384, 1);
  STG_AB(32768, 2);
  asm volatile("s_waitcnt vmcnt(8)" ::: "memory");
  __builtin_amdgcn_s_barrier();
  asm volatile("" ::: "memory");

#define STEP(BO, DO_STG, SBO, SKT, VMW, ENDBAR)                               \
  do {                                                                        \
    bf16x8 a0 = *(const bf16x8*)(Lds + (BO) + 0 * 1024 + aoff);               \
    bf16x8 a1 = *(const bf16x8*)(Lds + (BO) + 1 * 1024 + aoff);               \
    bf16x8 a2 = *(const bf16x8*)(Lds + (BO) + 2 * 1024 + aoff);               \
    bf16x8 a3 = *(const bf16x8*)(Lds + (BO) + 3 * 1024 + aoff);               \
    bf16x8 b0 = *(const bf16x8*)(Lds + (BO) + 0 * 1024 + boff);               \
    bf16x8 b1 = *(const bf16x8*)(Lds + (BO) + 1 * 1024 + boff);               \
    bf16x8 b2 = *(const bf16x8*)(Lds + (BO) + 2 * 1024 + boff);               \
    bf16x8 b3 = *(const bf16x8*)(Lds + (BO) + 3 * 1024 + boff);               \
    if (DO_STG) STG_AB(SBO, SKT);                                             \
    __builtin_amdgcn_s_setprio(1);                                            \
    acc[0][0] = MF(a0, b0, acc[0][0]);                                        \
    acc[0][1] = MF(a0, b1, acc[0][1]);                                        \
    acc[0][2] = MF(a0, b2, acc[0][2]);                                        \
    acc[0][3] = MF(a0, b3, acc[0][3]);                                        \
    acc[1][0] = MF(a1, b0, acc[1][0]);                                        \
    acc[1][1] = MF(a1, b1, acc[1][1]);                                        \
    acc[1][2] = MF(a1, b2, acc[1][2]);                                        \
    acc[1][3] = MF(a1, b3, acc[1][3]);                                        \
    acc[2][0] = MF(a2, b0, acc[2][0]);                                        \
    acc[2][1] = MF(a2, b1, acc[2][1]);                                        \
    acc[2][2] = MF(a2, b2, acc[2][2]);                                        \
    acc[2][3] = MF(a2, b3, acc[2][3]);                                        \
    acc[3][0] = MF(a3, b0, acc[3][0]);                                        \
    acc[3][1] = MF(a3, b1, acc[3][1]);                                        \
    acc[3][2] = MF(a3, b2, acc[3][2]);                                        \
    acc[3][3] = MF(a3, b3, acc[3][3]);                                        \
    __builtin_amdgcn_s_setprio(0);                                            \
    asm volatile(VMW ::: "memory");                                           \
    if (ENDBAR) {                                                             \
      __builtin_amdgcn_s_barrier();                                           \
      asm volatile("" ::: "memory");                                          \
    }                                                                         \
  } while (0)

#pragma unroll 1
  for (int tt = 0; tt < 29; ++tt) {
    int bo = (tt & 3) << 14;
    int sbo = ((tt + 3) & 3) << 14;
    STEP(bo, 1, sbo, tt + 3, "s_waitcnt vmcnt(8)", 1);
  }
  STEP((29 & 3) << 14, 0, 0, 0, "s_waitcnt vmcnt(4)", 1);
  STEP((30 & 3) << 14, 0, 0, 0, "s_waitcnt vmcnt(0)", 1);
  STEP((31 & 3) << 14, 0, 0, 0, "s_nop 0", 0);

#undef STEP
#undef STG_AB

  const float* bias = a.bias[job];
  short* out = a.out[job];
  int tshift = a.tshift[job], tmask = (1 << tshift) - 1, mode = a.mode[job];
  float scl = a.scale[job];
#pragma unroll
  for (int m = 0; m < 4; ++m) {
    int rowb = arow + wr * 64 + m * 16 + (g4 << 2);
#pragma unroll
    for (int n = 0; n < 4; ++n) {
      int col = brow + wc * 64 + n * 16 + l15;
      float bv = bias[col];
      int head = col >> 6, d = col & 63;
#pragma unroll
      for (int r = 0; r < 4; ++r) {
        int row = rowb + r;
        int bb = row >> tshift, tk = row & tmask;
        float val = (acc[m][n][r] + bv) * scl;
        size_t idx;
        if (mode == 0)
          idx = ((((size_t)bb * NHEAD + head) << tshift) + tk) * 64 + d;
        else
          idx = ((((size_t)bb * NHEAD + head) * 64 + d) << tshift) + tk;
        out[idx] = f2bf(val);
      }
    }
  }
}

// ---- kernel 4: swapped-QK^T 32x32 flash attention (r7 proven version) ------
__global__ __launch_bounds__(256, 3) void attn32(
    const short* __restrict__ qall, const short* __restrict__ kall,
    const short* __restrict__ vTall, const short* __restrict__ kqall,
    const short* __restrict__ kkall, const short* __restrict__ kvTall,
    const float* __restrict__ amask, const float* __restrict__ emask,
    float* __restrict__ out) {
  __shared__ char KT[2][8192];
  __shared__ char VT[2][8192];
  __shared__ float red[4][32];

  int lid = blockIdx.x;
  int id = (lid & 7) * 64 + (lid >> 3);
  int bh = id >> 3, qb = id & 7;
  int b = bh >> 4, h = bh & 15;
  int lane = threadIdx.x & 63, wave = threadIdx.x >> 6;
  int l31 = lane & 31, hi = lane >> 5, x7 = l31 & 7;
  int qrow0 = qb * 128 + wave * 32;

  bf16x8 qcur[4];
  {
    const short* qp = qall + ((size_t)bh * SEQ + qrow0 + l31) * 64;
#pragma unroll
    for (int i = 0; i < 4; ++i)
      qcur[i] = *(const bf16x8*)(qp + i * 16 + hi * 8);
  }

  const char* kb0 = (const char*)(kall + (size_t)bh * SEQ * 64);
  const char* vb0 = (const char*)(vTall + (size_t)bh * 64 * SEQ);
  const char* kb1 = (const char*)(kkall + (size_t)bh * KENC * 64);
  const char* vb1 = (const char*)(kvTall + (size_t)bh * 64 * KENC);
  const float* mpc = amask + (size_t)b * SEQ;

  auto STAGE = [&](int pb, const char* kb, const char* vb, size_t vrowb, int kt) {
    int t0 = threadIdx.x;
#pragma unroll
    for (int c = 0; c < 2; ++c) {
      int idx = c * 256 + t0;
      int row = idx >> 3, phys = idx & 7;
      int lg = phys ^ (row & 7);
      gload_lds16(kb + ((size_t)(kt * 64 + row)) * 128 + lg * 16,
                  KT[pb] + idx * 16);
      gload_lds16(vb + (size_t)row * vrowb + (size_t)kt * 128 + lg * 16,
                  VT[pb] + idx * 16);
    }
  };

  STAGE(0, kb0, vb0, SEQ * 2, 0);

  f32x16 ctx0, ctx1, c10, c11;
#pragma unroll
  for (int r = 0; r < 16; ++r) { ctx0[r] = 0.f; ctx1[r] = 0.f; c10[r] = 0.f; c11[r] = 0.f; }
  float mr = -1e30f, lr = 0.f;

#pragma unroll 1
  for (int t = 0; t < 24; ++t) {
    int p = t & 1;
    __syncthreads();
    if (t < 23) {
      int tn = t + 1;
      if (tn >= 16) STAGE(p ^ 1, kb1, vb1, KENC * 2, tn - 16);
      else          STAGE(p ^ 1, kb0, vb0, SEQ * 2, tn);
    }
    if (t == 16) {
      if (!hi) red[wave][l31] = lr;
      asm volatile("s_waitcnt lgkmcnt(0)" ::: "memory");
#pragma unroll
      for (int r2 = 0; r2 < 4; ++r2) {
        f4v lv = *(const f4v*)(&red[wave][r2 * 8 + 4 * hi]);
#pragma unroll
        for (int j2 = 0; j2 < 4; ++j2) {
          float li = __builtin_amdgcn_rcpf(lv[j2]);
          int r = r2 * 4 + j2;
          c10[r] = ctx0[r] * li;  ctx0[r] = 0.f;
          c11[r] = ctx1[r] * li;  ctx1[r] = 0.f;
        }
      }
      mr = -1e30f; lr = 0.f;
      const short* kqp = kqall + ((size_t)bh * SEQ + qrow0 + l31) * 64;
#pragma unroll
      for (int i = 0; i < 4; ++i)
        qcur[i] = *(const bf16x8*)(kqp + i * 16 + hi * 8);
      mpc = emask + (size_t)b * KENC;
    }
    int kt = (t >= 16) ? t - 16 : t;
    const char* Kp = KT[p];
    const char* Vp = VT[p];

    f32x16 s0, s1;
#pragma unroll
    for (int r = 0; r < 16; ++r) { s0[r] = 0.f; s1[r] = 0.f; }
    __builtin_amdgcn_s_setprio(1);
#pragma unroll
    for (int i = 0; i < 4; ++i) {
      bf16x8 kf = *(const bf16x8*)(Kp + (l31)*128 + (((2 * i + hi) ^ x7) << 4));
      s0 = __builtin_amdgcn_mfma_f32_32x32x16_bf16(kf, qcur[i], s0, 0, 0, 0);
    }
#pragma unroll
    for (int i = 0; i < 4; ++i) {
      bf16x8 kf = *(const bf16x8*)(Kp + (32 + l31) * 128 + (((2 * i + hi) ^ x7) << 4));
      s1 = __builtin_amdgcn_mfma_f32_32x32x16_bf16(kf, qcur[i], s1, 0, 0, 0);
    }
    __builtin_amdgcn_s_setprio(0);

    const float* mp = mpc + kt * 64;
#pragma unroll
    for (int r2 = 0; r2 < 4; ++r2) {
      f4v ma = *(const f4v*)(mp + r2 * 8 + 4 * hi);
      f4v mb = *(const f4v*)(mp + 32 + r2 * 8 + 4 * hi);
#pragma unroll
      for (int j2 = 0; j2 < 4; ++j2) {
        s0[r2 * 4 + j2] = fmaf(ma[j2], LOG2E, s0[r2 * 4 + j2]);
        s1[r2 * 4 + j2] = fmaf(mb[j2], LOG2E, s1[r2 * 4 + j2]);
      }
    }

    float mx = s0[0];
#pragma unroll
    for (int r = 1; r < 16; ++r) mx = fmaxf(mx, s0[r]);
#pragma unroll
    for (int r = 0; r < 16; ++r) mx = fmaxf(mx, s1[r]);
    mx = fmaxf(mx, __int_as_float(__shfl_xor(__float_as_int(mx), 32)));

    if (!__all(mx <= mr + 12.f)) {
      float mn = fmaxf(mr, mx);
      float scl = __builtin_amdgcn_exp2f(mr - mn);
      mr = mn; lr *= scl;
      if (!hi) red[wave][l31] = scl;
      asm volatile("s_waitcnt lgkmcnt(0)" ::: "memory");
#pragma unroll
      for (int r2 = 0; r2 < 4; ++r2) {
        f4v sv = *(const f4v*)(&red[wave][r2 * 8 + 4 * hi]);
#pragma unroll
        for (int j2 = 0; j2 < 4; ++j2) {
          ctx0[r2 * 4 + j2] *= sv[j2];
          ctx1[r2 * 4 + j2] *= sv[j2];
        }
      }
    }

    float rs = 0.f;
#pragma unroll
    for (int r = 0; r < 16; ++r) { s0[r] = __builtin_amdgcn_exp2f(s0[r] - mr); rs += s0[r]; }
#pragma unroll
    for (int r = 0; r < 16; ++r) { s1[r] = __builtin_amdgcn_exp2f(s1[r] - mr); rs += s1[r]; }
    rs += __int_as_float(__shfl_xor(__float_as_int(rs), 32));
    lr += rs;

#pragma unroll
    for (int s = 0; s < 2; ++s) {
      const f32x16& sv = s ? s1 : s0;
      unsigned W[8];
#pragma unroll
      for (int r2 = 0; r2 < 4; ++r2) {
        asm("v_cvt_pk_bf16_f32 %0, %1, %2"
            : "=v"(W[r2 * 2]) : "v"(sv[r2 * 4 + 0]), "v"(sv[r2 * 4 + 1]));
        asm("v_cvt_pk_bf16_f32 %0, %1, %2"
            : "=v"(W[r2 * 2 + 1]) : "v"(sv[r2 * 4 + 2]), "v"(sv[r2 * 4 + 3]));
      }
#pragma unroll
      for (int jr = 0; jr < 2; ++jr) {
        unsigned sendA = hi ? W[(2 * jr) * 2]     : W[(2 * jr + 1) * 2];
        unsigned sendB = hi ? W[(2 * jr) * 2 + 1] : W[(2 * jr + 1) * 2 + 1];
        unsigned rA = (unsigned)__shfl_xor((int)sendA, 32);
        unsigned rB = (unsigned)__shfl_xor((int)sendB, 32);
        union { unsigned u[4]; bf16x8 v; } pa;
        if (!hi) { pa.u[0] = W[2 * jr * 2]; pa.u[1] = W[2 * jr * 2 + 1];
                   pa.u[2] = rA;            pa.u[3] = rB; }
        else     { pa.u[0] = rA;            pa.u[1] = rB;
                   pa.u[2] = W[(2 * jr + 1) * 2]; pa.u[3] = W[(2 * jr + 1) * 2 + 1]; }
        int j = s * 2 + jr;
        __builtin_amdgcn_s_setprio(1);
        bf16x8 vf0 = *(const bf16x8*)(Vp + (l31)*128 + (((2 * j + hi) ^ x7) << 4));
        ctx0 = __builtin_amdgcn_mfma_f32_32x32x16_bf16(pa.v, vf0, ctx0, 0, 0, 0);
        bf16x8 vf1 = *(const bf16x8*)(Vp + (32 + l31) * 128 + (((2 * j + hi) ^ x7) << 4));
        ctx1 = __builtin_amdgcn_mfma_f32_32x32x16_bf16(pa.v, vf1, ctx1, 0, 0, 0);
        __builtin_amdgcn_s_setprio(0);
      }
    }
  }

  if (!hi) red[wave][l31] = lr;
  asm volatile("s_waitcnt lgkmcnt(0)" ::: "memory");
  float* op = out + ((size_t)b * SEQ) * HDIM + h * 64 + l31;
#pragma unroll
  for (int r2 = 0; r2 < 4; ++r2) {
    f4v lv = *(const f4v*)(&red[wave][r2 * 8 + 4 * hi]);
#pragma unroll
    for (int j2 = 0; j2 < 4; ++j2) {
      float li = __builtin_amdgcn_rcpf(lv[j2]);
      int s = qrow0 + r2 * 8 + 4 * hi + j2;
      int r = r2 * 4 + j2;
      op[(size_t)s * HDIM]      = 0.5f * (c10[r] + ctx0[r] * li);
      op[(size_t)s * HDIM + 32] = 0.5f * (c11[r] + ctx1[r] * li);
    }
  }
}

// ---- host launcher ---------------------------------------------------------
extern "C" void kernel_launch(void* const* d_in, const int* in_sizes, int n_in,
                              void* d_out, int out_size, void* d_ws, size_t ws_size,
                              hipStream_t stream) {
  const float* hid = (const float*)d_in[0];
  const float* enc = (const float*)d_in[1];
  const float* amask = (const float*)d_in[2];
  const float* emask = (const float*)d_in[3];

  char* ws = (char*)d_ws;
  short* hbf = (short*)(ws);                        // 8 MB  [B*S,H] bf16
  short* ebf = (short*)(ws + (8u << 20));           // 4 MB  [B*K,H]
  short* wt = (short*)(ws + (12u << 20));           // 12 MB 6x [n][k]
  short* qo = (short*)(ws + (24u << 20));           // 8 MB  [B,NH,S,HD]
  short* ko = (short*)(ws + (32u << 20));           // 8 MB
  short* vT = (short*)(ws + (40u << 20));           // 8 MB  [B,NH,HD,S]
  short* kqo = (short*)(ws + (48u << 20));          // 8 MB
  short* kko = (short*)(ws + (56u << 20));          // 4 MB  [B,NH,K,HD]
  short* kvT = (short*)(ws + (60u << 20));          // 4 MB  [B,NH,HD,K]

  PrepArgs wa;
  for (int j = 0; j < 6; ++j) wa.W[j] = (const float*)d_in[4 + 2 * j];
  prep<<<12288, 256, 0, stream>>>(wa, wt, hid, hbf, (BATCH * SEQ * HDIM) / 4,
                                  enc, ebf, (BATCH * KENC * HDIM) / 4);

  ProjArgs pa;
  const short* Xs[6] = {hbf, hbf, hbf, hbf, ebf, ebf};
  short* outs[6] = {qo, ko, vT, kqo, kko, kvT};
  const int Ms[6] = {4096, 4096, 4096, 4096, 2048, 2048};
  const int tsh[6] = {10, 10, 10, 10, 9, 9};
  const int md[6] = {0, 0, 1, 0, 0, 1};
  const float qscale = 0.125f * LOG2E;
  const float scl[6] = {qscale, 1.f, 1.f, qscale, 1.f, 1.f};
  for (int j = 0; j < 6; ++j) {
    pa.X[j] = Xs[j];
    pa.Wt[j] = wt + (size_t)j * (HDIM * HDIM);
    pa.bias[j] = (const float*)d_in[5 + 2 * j];
    pa.out[j] = outs[j];
    pa.M[j] = Ms[j];
    pa.tshift[j] = tsh[j];
    pa.mode[j] = md[j];
    pa.scale[j] = scl[j];
  }
  proj_gemm<<<dim3(8, 32, 6), 256, 0, stream>>>(pa);

  attn32<<<512, 256, 0, stream>>>(qo, ko, vT, kqo, kko, kvT, amask, emask,
                                  (float*)d_out);
}

// Round 12
// 143.113 us; speedup vs baseline: 1.2610x; 1.0682x over previous
//
#include <hip/hip_runtime.h>

// ---- constants -------------------------------------------------------------
#define BATCH 4
#define SEQ   1024
#define KENC  512
#define HDIM  1024
#define NHEAD 16
#define HD    64
#define LOG2E 1.44269504088896340736f

typedef __attribute__((ext_vector_type(8))) short bf16x8;
typedef __attribute__((ext_vector_type(4))) float f32x4;
typedef __attribute__((ext_vector_type(16))) float f32x16;
typedef __attribute__((ext_vector_type(4))) float f4v;
typedef __attribute__((ext_vector_type(4))) short s4v;

__device__ __forceinline__ short f2bf(float f) {
  unsigned u = __float_as_uint(f);
  u += 0x7fffu + ((u >> 16) & 1u);   // RNE
  return (short)(u >> 16);
}

__device__ __forceinline__ void gload_lds16(const void* g, void* l) {
  __builtin_amdgcn_global_load_lds(
      (const __attribute__((address_space(1))) void*)g,
      (__attribute__((address_space(3))) void*)l, 16, 0, 0);
}

#define MF(A, B, C) __builtin_amdgcn_mfma_f32_16x16x32_bf16((A), (B), (C), 0, 0, 0)

// ---- kernel 1: fused prep — weight cast+transpose AND activation casts -----
struct PrepArgs { const float* W[6]; };

__global__ __launch_bounds__(256) void prep(PrepArgs a, short* __restrict__ wt,
                                            const float* __restrict__ hid,
                                            short* __restrict__ hbf, int n4h,
                                            const float* __restrict__ enc,
                                            short* __restrict__ ebf, int n4e) {
  __shared__ float t[32][33];
  int blk = blockIdx.x;
  if (blk < 6144) {
    int j = blk >> 10;
    int r = blk & 1023;
    int cb = (r & 31) * 32, rb = (r >> 5) * 32;
    const float* W = a.W[j];
    short* dst = wt + (size_t)j * (HDIM * HDIM);
    int tx = threadIdx.x & 31, ty = threadIdx.x >> 5;
#pragma unroll
    for (int rr = 0; rr < 4; ++rr)
      t[ty + rr * 8][tx] = W[(size_t)(rb + ty + rr * 8) * HDIM + cb + tx];
    __syncthreads();
#pragma unroll
    for (int rr = 0; rr < 4; ++rr)
      dst[(size_t)(cb + ty + rr * 8) * HDIM + rb + tx] = f2bf(t[tx][ty + rr * 8]);
  } else {
    int i = (blk - 6144) * 256 + threadIdx.x;
    const float* s;
    short* d;
    int j;
    if (i < n4h) { s = hid; d = hbf; j = i; }
    else { j = i - n4h; if (j >= n4e) return; s = enc; d = ebf; }
    f4v v = ((const f4v*)s)[j];
    s4v o;
#pragma unroll
    for (int k = 0; k < 4; ++k) o[k] = f2bf(v[k]);
    ((s4v*)d)[j] = o;
  }
}

// ---- kernel 3: projection GEMM (round-7 best: 75.3us) ----------------------
// 128x128 tile, BK=32, quad-buffer with LITERAL buffer offsets (unrolled x4),
// fine-interleaved 2-phase GSTEP, counted vmcnt(4), single barrier per K-step.
struct ProjArgs {
  const short* X[6];
  const short* Wt[6];
  const float* bias[6];
  short* out[6];
  int M[6];
  int tshift[6];
  int mode[6];
  float scale[6];
};

__global__ __launch_bounds__(256) void proj_gemm(ProjArgs a) {
  int job = blockIdx.z;
  int M = a.M[job];
  int by = blockIdx.y;
  if (by * 128 >= M) return;
  int bx = blockIdx.x;
  const short* X = a.X[job];
  const short* W = a.Wt[job];

  __shared__ __align__(16) char Lds[65536];   // 4 bufs x (A 8K | B 8K)

  int tid = threadIdx.x, lane = tid & 63, wave = tid >> 6;
  int wr = wave >> 1, wc = wave & 1;
  int l15 = lane & 15, g4 = lane >> 4;

  f32x4 acc[4][4];
#pragma unroll
  for (int m = 0; m < 4; ++m)
#pragma unroll
    for (int n = 0; n < 4; ++n)
#pragma unroll
      for (int r = 0; r < 4; ++r) acc[m][n][r] = 0.0f;

  int arow = by * 128, brow = bx * 128;
  const int crow = lane >> 2;
  const int sgrp = (lane & 3) ^ ((lane >> 2) & 3) ^ (lane >> 4);
  const int rsw = (lane & 3) ^ (l15 >> 2);

  const char* Xb = (const char*)X;
  const char* Wb = (const char*)W;
  const size_t sac0 = ((size_t)(arow + 32 * wave + crow) * HDIM + sgrp * 8) * 2;
  const size_t sac1 = sac0 + (size_t)16 * HDIM * 2;
  const size_t sbc0 = ((size_t)(brow + 32 * wave + crow) * HDIM + sgrp * 8) * 2;
  const size_t sbc1 = sbc0 + (size_t)16 * HDIM * 2;
  const int ldA0 = wave * 2048, ldA1 = ldA0 + 1024;
  const int ldB0 = 8192 + ldA0, ldB1 = ldB0 + 1024;

  const int aoff = wr * 4096 + l15 * 64 + ((g4 ^ rsw) << 4);
  const int boff = 8192 + wc * 4096 + l15 * 64 + ((g4 ^ rsw) << 4);

#define STG_A(SBO, SKT)                                                  \
  do {                                                                   \
    gload_lds16(Xb + sac0 + (size_t)(SKT) * 64, Lds + (SBO) + ldA0);     \
    gload_lds16(Xb + sac1 + (size_t)(SKT) * 64, Lds + (SBO) + ldA1);     \
  } while (0)
#define STG_B(SBO, SKT)                                                  \
  do {                                                                   \
    gload_lds16(Wb + sbc0 + (size_t)(SKT) * 64, Lds + (SBO) + ldB0);     \
    gload_lds16(Wb + sbc1 + (size_t)(SKT) * 64, Lds + (SBO) + ldB1);     \
  } while (0)

  // prologue: tiles 0,1,2 -> bufs 0,1,2; publish tiles 0,1.
  STG_A(0, 0);     STG_B(0, 0);
  STG_A(16384, 1); STG_B(16384, 1);
  STG_A(32768, 2); STG_B(32768, 2);
  asm volatile("s_waitcnt vmcnt(4)" ::: "memory");
  __builtin_amdgcn_s_barrier();
  asm volatile("" ::: "memory");

  bf16x8 xa0, xa1, xb0, xb1, xb2, xb3;
  bf16x8 ya0, ya1, yb0, yb1, yb2, yb3;

  xa0 = *(const bf16x8*)(Lds + 0 * 1024 + aoff);
  xa1 = *(const bf16x8*)(Lds + 1 * 1024 + aoff);
  xb0 = *(const bf16x8*)(Lds + 0 * 1024 + boff);
  xb1 = *(const bf16x8*)(Lds + 1 * 1024 + boff);
  xb2 = *(const bf16x8*)(Lds + 2 * 1024 + boff);
  xb3 = *(const bf16x8*)(Lds + 3 * 1024 + boff);

#define GSTEP_I(BO, BON, CA0, CA1, CB0, CB1, CB2, CB3, NA0, NA1, NB0, NB1,    \
                NB2, NB3, DO_STG, SBO, SKT, DO_NEXT, VMASM, DO_BAR)           \
  do {                                                                        \
    bf16x8 q2 = *(const bf16x8*)(Lds + (BO) + 2 * 1024 + aoff);               \
    bf16x8 q3 = *(const bf16x8*)(Lds + (BO) + 3 * 1024 + aoff);               \
    if (DO_STG) STG_A(SBO, SKT);                                              \
    __builtin_amdgcn_s_setprio(1);                                            \
    acc[0][0] = MF(CA0, CB0, acc[0][0]);                                      \
    acc[0][1] = MF(CA0, CB1, acc[0][1]);                                      \
    acc[0][2] = MF(CA0, CB2, acc[0][2]);                                      \
    acc[0][3] = MF(CA0, CB3, acc[0][3]);                                      \
    acc[1][0] = MF(CA1, CB0, acc[1][0]);                                      \
    acc[1][1] = MF(CA1, CB1, acc[1][1]);                                      \
    acc[1][2] = MF(CA1, CB2, acc[1][2]);                                      \
    acc[1][3] = MF(CA1, CB3, acc[1][3]);                                      \
    __builtin_amdgcn_s_setprio(0);                                            \
    if (DO_NEXT) {                                                            \
      NA0 = *(const bf16x8*)(Lds + (BON) + 0 * 1024 + aoff);                  \
      NA1 = *(const bf16x8*)(Lds + (BON) + 1 * 1024 + aoff);                  \
      NB0 = *(const bf16x8*)(Lds + (BON) + 0 * 1024 + boff);                  \
      NB1 = *(const bf16x8*)(Lds + (BON) + 1 * 1024 + boff);                  \
      NB2 = *(const bf16x8*)(Lds + (BON) + 2 * 1024 + boff);                  \
      NB3 = *(const bf16x8*)(Lds + (BON) + 3 * 1024 + boff);                  \
    }                                                                         \
    if (DO_STG) STG_B(SBO, SKT);                                              \
    __builtin_amdgcn_s_setprio(1);                                            \
    acc[2][0] = MF(q2, CB0, acc[2][0]);                                       \
    acc[2][1] = MF(q2, CB1, acc[2][1]);                                       \
    acc[2][2] = MF(q2, CB2, acc[2][2]);                                       \
    acc[2][3] = MF(q2, CB3, acc[2][3]);                                       \
    acc[3][0] = MF(q3, CB0, acc[3][0]);                                       \
    acc[3][1] = MF(q3, CB1, acc[3][1]);                                       \
    acc[3][2] = MF(q3, CB2, acc[3][2]);                                       \
    acc[3][3] = MF(q3, CB3, acc[3][3]);                                       \
    __builtin_amdgcn_s_setprio(0);                                            \
    asm volatile(VMASM ::: "memory");                                         \
    if (DO_BAR) {                                                             \
      __builtin_amdgcn_s_barrier();                                           \
      asm volatile("" ::: "memory");                                          \
    }                                                                         \
  } while (0)
#define GSTEP(...) GSTEP_I(__VA_ARGS__)

#define XSET xa0, xa1, xb0, xb1, xb2, xb3
#define YSET ya0, ya1, yb0, yb1, yb2, yb3

#pragma unroll 1
  for (int it = 0; it < 7; ++it) {
    int t0 = it * 4;
    GSTEP(0,     16384, XSET, YSET, 1, 49152, t0 + 3, 1, "s_waitcnt vmcnt(4)", 1);
    GSTEP(16384, 32768, YSET, XSET, 1, 0,     t0 + 4, 1, "s_waitcnt vmcnt(4)", 1);
    GSTEP(32768, 49152, XSET, YSET, 1, 16384, t0 + 5, 1, "s_waitcnt vmcnt(4)", 1);
    GSTEP(49152, 0,     YSET, XSET, 1, 32768, t0 + 6, 1, "s_waitcnt vmcnt(4)", 1);
  }
  GSTEP(0,     16384, XSET, YSET, 1, 49152, 31, 1, "s_waitcnt vmcnt(4)", 1);
  GSTEP(16384, 32768, YSET, XSET, 0, 0, 0,      1, "s_waitcnt vmcnt(0)", 1);
  GSTEP(32768, 49152, XSET, YSET, 0, 0, 0,      1, "s_nop 0", 1);
  GSTEP(49152, 0,     YSET, XSET, 0, 0, 0,      0, "s_nop 0", 0);

#undef GSTEP
#undef GSTEP_I
#undef XSET
#undef YSET
#undef STG_A
#undef STG_B

  const float* bias = a.bias[job];
  short* out = a.out[job];
  int tshift = a.tshift[job], tmask = (1 << tshift) - 1, mode = a.mode[job];
  float scl = a.scale[job];
#pragma unroll
  for (int m = 0; m < 4; ++m) {
    int rowb = arow + wr * 64 + m * 16 + (g4 << 2);
#pragma unroll
    for (int n = 0; n < 4; ++n) {
      int col = brow + wc * 64 + n * 16 + l15;
      float bv = bias[col];
      int head = col >> 6, d = col & 63;
#pragma unroll
      for (int r = 0; r < 4; ++r) {
        int row = rowb + r;
        int bb = row >> tshift, tk = row & tmask;
        float val = (acc[m][n][r] + bv) * scl;
        size_t idx;
        if (mode == 0)
          idx = ((((size_t)bb * NHEAD + head) << tshift) + tk) * 64 + d;
        else
          idx = ((((size_t)bb * NHEAD + head) * 64 + d) << tshift) + tk;
        out[idx] = f2bf(val);
      }
    }
  }
}

// ---- kernel 4: swapped-QK^T 32x32 flash attention (r7 proven version) ------
__global__ __launch_bounds__(256, 3) void attn32(
    const short* __restrict__ qall, const short* __restrict__ kall,
    const short* __restrict__ vTall, const short* __restrict__ kqall,
    const short* __restrict__ kkall, const short* __restrict__ kvTall,
    const float* __restrict__ amask, const float* __restrict__ emask,
    float* __restrict__ out) {
  __shared__ char KT[2][8192];
  __shared__ char VT[2][8192];
  __shared__ float red[4][32];

  int lid = blockIdx.x;
  int id = (lid & 7) * 64 + (lid >> 3);
  int bh = id >> 3, qb = id & 7;
  int b = bh >> 4, h = bh & 15;
  int lane = threadIdx.x & 63, wave = threadIdx.x >> 6;
  int l31 = lane & 31, hi = lane >> 5, x7 = l31 & 7;
  int qrow0 = qb * 128 + wave * 32;

  bf16x8 qcur[4];
  {
    const short* qp = qall + ((size_t)bh * SEQ + qrow0 + l31) * 64;
#pragma unroll
    for (int i = 0; i < 4; ++i)
      qcur[i] = *(const bf16x8*)(qp + i * 16 + hi * 8);
  }

  const char* kb0 = (const char*)(kall + (size_t)bh * SEQ * 64);
  const char* vb0 = (const char*)(vTall + (size_t)bh * 64 * SEQ);
  const char* kb1 = (const char*)(kkall + (size_t)bh * KENC * 64);
  const char* vb1 = (const char*)(kvTall + (size_t)bh * 64 * KENC);
  const float* mpc = amask + (size_t)b * SEQ;

  auto STAGE = [&](int pb, const char* kb, const char* vb, size_t vrowb, int kt) {
    int t0 = threadIdx.x;
#pragma unroll
    for (int c = 0; c < 2; ++c) {
      int idx = c * 256 + t0;
      int row = idx >> 3, phys = idx & 7;
      int lg = phys ^ (row & 7);
      gload_lds16(kb + ((size_t)(kt * 64 + row)) * 128 + lg * 16,
                  KT[pb] + idx * 16);
      gload_lds16(vb + (size_t)row * vrowb + (size_t)kt * 128 + lg * 16,
                  VT[pb] + idx * 16);
    }
  };

  STAGE(0, kb0, vb0, SEQ * 2, 0);

  f32x16 ctx0, ctx1, c10, c11;
#pragma unroll
  for (int r = 0; r < 16; ++r) { ctx0[r] = 0.f; ctx1[r] = 0.f; c10[r] = 0.f; c11[r] = 0.f; }
  float mr = -1e30f, lr = 0.f;

#pragma unroll 1
  for (int t = 0; t < 24; ++t) {
    int p = t & 1;
    __syncthreads();
    if (t < 23) {
      int tn = t + 1;
      if (tn >= 16) STAGE(p ^ 1, kb1, vb1, KENC * 2, tn - 16);
      else          STAGE(p ^ 1, kb0, vb0, SEQ * 2, tn);
    }
    if (t == 16) {
      if (!hi) red[wave][l31] = lr;
      asm volatile("s_waitcnt lgkmcnt(0)" ::: "memory");
#pragma unroll
      for (int r2 = 0; r2 < 4; ++r2) {
        f4v lv = *(const f4v*)(&red[wave][r2 * 8 + 4 * hi]);
#pragma unroll
        for (int j2 = 0; j2 < 4; ++j2) {
          float li = __builtin_amdgcn_rcpf(lv[j2]);
          int r = r2 * 4 + j2;
          c10[r] = ctx0[r] * li;  ctx0[r] = 0.f;
          c11[r] = ctx1[r] * li;  ctx1[r] = 0.f;
        }
      }
      mr = -1e30f; lr = 0.f;
      const short* kqp = kqall + ((size_t)bh * SEQ + qrow0 + l31) * 64;
#pragma unroll
      for (int i = 0; i < 4; ++i)
        qcur[i] = *(const bf16x8*)(kqp + i * 16 + hi * 8);
      mpc = emask + (size_t)b * KENC;
    }
    int kt = (t >= 16) ? t - 16 : t;
    const char* Kp = KT[p];
    const char* Vp = VT[p];

    f32x16 s0, s1;
#pragma unroll
    for (int r = 0; r < 16; ++r) { s0[r] = 0.f; s1[r] = 0.f; }
    __builtin_amdgcn_s_setprio(1);
#pragma unroll
    for (int i = 0; i < 4; ++i) {
      bf16x8 kf = *(const bf16x8*)(Kp + (l31)*128 + (((2 * i + hi) ^ x7) << 4));
      s0 = __builtin_amdgcn_mfma_f32_32x32x16_bf16(kf, qcur[i], s0, 0, 0, 0);
    }
#pragma unroll
    for (int i = 0; i < 4; ++i) {
      bf16x8 kf = *(const bf16x8*)(Kp + (32 + l31) * 128 + (((2 * i + hi) ^ x7) << 4));
      s1 = __builtin_amdgcn_mfma_f32_32x32x16_bf16(kf, qcur[i], s1, 0, 0, 0);
    }
    __builtin_amdgcn_s_setprio(0);

    const float* mp = mpc + kt * 64;
#pragma unroll
    for (int r2 = 0; r2 < 4; ++r2) {
      f4v ma = *(const f4v*)(mp + r2 * 8 + 4 * hi);
      f4v mb = *(const f4v*)(mp + 32 + r2 * 8 + 4 * hi);
#pragma unroll
      for (int j2 = 0; j2 < 4; ++j2) {
        s0[r2 * 4 + j2] = fmaf(ma[j2], LOG2E, s0[r2 * 4 + j2]);
        s1[r2 * 4 + j2] = fmaf(mb[j2], LOG2E, s1[r2 * 4 + j2]);
      }
    }

    float mx = s0[0];
#pragma unroll
    for (int r = 1; r < 16; ++r) mx = fmaxf(mx, s0[r]);
#pragma unroll
    for (int r = 0; r < 16; ++r) mx = fmaxf(mx, s1[r]);
    mx = fmaxf(mx, __int_as_float(__shfl_xor(__float_as_int(mx), 32)));

    if (!__all(mx <= mr + 12.f)) {
      float mn = fmaxf(mr, mx);
      float scl = __builtin_amdgcn_exp2f(mr - mn);
      mr = mn; lr *= scl;
      if (!hi) red[wave][l31] = scl;
      asm volatile("s_waitcnt lgkmcnt(0)" ::: "memory");
#pragma unroll
      for (int r2 = 0; r2 < 4; ++r2) {
        f4v sv = *(const f4v*)(&red[wave][r2 * 8 + 4 * hi]);
#pragma unroll
        for (int j2 = 0; j2 < 4; ++j2) {
          ctx0[r2 * 4 + j2] *= sv[j2];
          ctx1[r2 * 4 + j2] *= sv[j2];
        }
      }
    }

    float rs = 0.f;
#pragma unroll
    for (int r = 0; r < 16; ++r) { s0[r] = __builtin_amdgcn_exp2f(s0[r] - mr); rs += s0[r]; }
#pragma unroll
    for (int r = 0; r < 16; ++r) { s1[r] = __builtin_amdgcn_exp2f(s1[r] - mr); rs += s1[r]; }
    rs += __int_as_float(__shfl_xor(__float_as_int(rs), 32));
    lr += rs;

#pragma unroll
    for (int s = 0; s < 2; ++s) {
      const f32x16& sv = s ? s1 : s0;
      unsigned W[8];
#pragma unroll
      for (int r2 = 0; r2 < 4; ++r2) {
        asm("v_cvt_pk_bf16_f32 %0, %1, %2"
            : "=v"(W[r2 * 2]) : "v"(sv[r2 * 4 + 0]), "v"(sv[r2 * 4 + 1]));
        asm("v_cvt_pk_bf16_f32 %0, %1, %2"
            : "=v"(W[r2 * 2 + 1]) : "v"(sv[r2 * 4 + 2]), "v"(sv[r2 * 4 + 3]));
      }
#pragma unroll
      for (int jr = 0; jr < 2; ++jr) {
        unsigned sendA = hi ? W[(2 * jr) * 2]     : W[(2 * jr + 1) * 2];
        unsigned sendB = hi ? W[(2 * jr) * 2 + 1] : W[(2 * jr + 1) * 2 + 1];
        unsigned rA = (unsigned)__shfl_xor((int)sendA, 32);
        unsigned rB = (unsigned)__shfl_xor((int)sendB, 32);
        union { unsigned u[4]; bf16x8 v; } pa;
        if (!hi) { pa.u[0] = W[2 * jr * 2]; pa.u[1] = W[2 * jr * 2 + 1];
                   pa.u[2] = rA;            pa.u[3] = rB; }
        else     { pa.u[0] = rA;            pa.u[1] = rB;
                   pa.u[2] = W[(2 * jr + 1) * 2]; pa.u[3] = W[(2 * jr + 1) * 2 + 1]; }
        int j = s * 2 + jr;
        __builtin_amdgcn_s_setprio(1);
        bf16x8 vf0 = *(const bf16x8*)(Vp + (l31)*128 + (((2 * j + hi) ^ x7) << 4));
        ctx0 = __builtin_amdgcn_mfma_f32_32x32x16_bf16(pa.v, vf0, ctx0, 0, 0, 0);
        bf16x8 vf1 = *(const bf16x8*)(Vp + (32 + l31) * 128 + (((2 * j + hi) ^ x7) << 4));
        ctx1 = __builtin_amdgcn_mfma_f32_32x32x16_bf16(pa.v, vf1, ctx1, 0, 0, 0);
        __builtin_amdgcn_s_setprio(0);
      }
    }
  }

  if (!hi) red[wave][l31] = lr;
  asm volatile("s_waitcnt lgkmcnt(0)" ::: "memory");
  float* op = out + ((size_t)b * SEQ) * HDIM + h * 64 + l31;
#pragma unroll
  for (int r2 = 0; r2 < 4; ++r2) {
    f4v lv = *(const f4v*)(&red[wave][r2 * 8 + 4 * hi]);
#pragma unroll
    for (int j2 = 0; j2 < 4; ++j2) {
      float li = __builtin_amdgcn_rcpf(lv[j2]);
      int s = qrow0 + r2 * 8 + 4 * hi + j2;
      int r = r2 * 4 + j2;
      op[(size_t)s * HDIM]      = 0.5f * (c10[r] + ctx0[r] * li);
      op[(size_t)s * HDIM + 32] = 0.5f * (c11[r] + ctx1[r] * li);
    }
  }
}

// ---- host launcher ---------------------------------------------------------
extern "C" void kernel_launch(void* const* d_in, const int* in_sizes, int n_in,
                              void* d_out, int out_size, void* d_ws, size_t ws_size,
                              hipStream_t stream) {
  const float* hid = (const float*)d_in[0];
  const float* enc = (const float*)d_in[1];
  const float* amask = (const float*)d_in[2];
  const float* emask = (const float*)d_in[3];

  char* ws = (char*)d_ws;
  short* hbf = (short*)(ws);                        // 8 MB  [B*S,H] bf16
  short* ebf = (short*)(ws + (8u << 20));           // 4 MB  [B*K,H]
  short* wt = (short*)(ws + (12u << 20));           // 12 MB 6x [n][k]
  short* qo = (short*)(ws + (24u << 20));           // 8 MB  [B,NH,S,HD]
  short* ko = (short*)(ws + (32u << 20));           // 8 MB
  short* vT = (short*)(ws + (40u << 20));           // 8 MB  [B,NH,HD,S]
  short* kqo = (short*)(ws + (48u << 20));          // 8 MB
  short* kko = (short*)(ws + (56u << 20));          // 4 MB  [B,NH,K,HD]
  short* kvT = (short*)(ws + (60u << 20));          // 4 MB  [B,NH,HD,K]

  PrepArgs wa;
  for (int j = 0; j < 6; ++j) wa.W[j] = (const float*)d_in[4 + 2 * j];
  prep<<<12288, 256, 0, stream>>>(wa, wt, hid, hbf, (BATCH * SEQ * HDIM) / 4,
                                  enc, ebf, (BATCH * KENC * HDIM) / 4);

  ProjArgs pa;
  const short* Xs[6] = {hbf, hbf, hbf, hbf, ebf, ebf};
  short* outs[6] = {qo, ko, vT, kqo, kko, kvT};
  const int Ms[6] = {4096, 4096, 4096, 4096, 2048, 2048};
  const int tsh[6] = {10, 10, 10, 10, 9, 9};
  const int md[6] = {0, 0, 1, 0, 0, 1};
  const float qscale = 0.125f * LOG2E;
  const float scl[6] = {qscale, 1.f, 1.f, qscale, 1.f, 1.f};
  for (int j = 0; j < 6; ++j) {
    pa.X[j] = Xs[j];
    pa.Wt[j] = wt + (size_t)j * (HDIM * HDIM);
    pa.bias[j] = (const float*)d_in[5 + 2 * j];
    pa.out[j] = outs[j];
    pa.M[j] = Ms[j];
    pa.tshift[j] = tsh[j];
    pa.mode[j] = md[j];
    pa.scale[j] = scl[j];
  }
  proj_gemm<<<dim3(8, 32, 6), 256, 0, stream>>>(pa);

  attn32<<<512, 256, 0, stream>>>(qo, ko, vT, kqo, kko, kvT, amask, emask,
                                  (float*)d_out);
}

// Round 13
// 139.741 us; speedup vs baseline: 1.2914x; 1.0241x over previous
//
#include <hip/hip_runtime.h>

// ---- constants -------------------------------------------------------------
#define BATCH 4
#define SEQ   1024
#define KENC  512
#define HDIM  1024
#define NHEAD 16
#define HD    64
#define LOG2E 1.44269504088896340736f

typedef __attribute__((ext_vector_type(8))) short bf16x8;
typedef __attribute__((ext_vector_type(4))) float f32x4;
typedef __attribute__((ext_vector_type(16))) float f32x16;
typedef __attribute__((ext_vector_type(4))) float f4v;
typedef __attribute__((ext_vector_type(4))) short s4v;

__device__ __forceinline__ short f2bf(float f) {
  unsigned u = __float_as_uint(f);
  u += 0x7fffu + ((u >> 16) & 1u);   // RNE
  return (short)(u >> 16);
}

__device__ __forceinline__ void gload_lds16(const void* g, void* l) {
  __builtin_amdgcn_global_load_lds(
      (const __attribute__((address_space(1))) void*)g,
      (__attribute__((address_space(3))) void*)l, 16, 0, 0);
}

// depth-5 pairwise trees (vs 31-op serial chains: ~25cy vs ~150cy crit path)
__device__ __forceinline__ float tmax16(const f32x16& v) {
  float a0 = fmaxf(v[0], v[1]),   a1 = fmaxf(v[2], v[3]);
  float a2 = fmaxf(v[4], v[5]),   a3 = fmaxf(v[6], v[7]);
  float a4 = fmaxf(v[8], v[9]),   a5 = fmaxf(v[10], v[11]);
  float a6 = fmaxf(v[12], v[13]), a7 = fmaxf(v[14], v[15]);
  float b0 = fmaxf(a0, a1), b1 = fmaxf(a2, a3);
  float b2 = fmaxf(a4, a5), b3 = fmaxf(a6, a7);
  return fmaxf(fmaxf(b0, b1), fmaxf(b2, b3));
}
__device__ __forceinline__ float tsum16(const f32x16& v) {
  float a0 = v[0] + v[1],   a1 = v[2] + v[3];
  float a2 = v[4] + v[5],   a3 = v[6] + v[7];
  float a4 = v[8] + v[9],   a5 = v[10] + v[11];
  float a6 = v[12] + v[13], a7 = v[14] + v[15];
  float b0 = a0 + a1, b1 = a2 + a3, b2 = a4 + a5, b3 = a6 + a7;
  return (b0 + b1) + (b2 + b3);
}

#define MF(A, B, C) __builtin_amdgcn_mfma_f32_16x16x32_bf16((A), (B), (C), 0, 0, 0)

// ---- kernel 1: fused prep — weight cast+transpose AND activation casts -----
struct PrepArgs { const float* W[6]; };

__global__ __launch_bounds__(256) void prep(PrepArgs a, short* __restrict__ wt,
                                            const float* __restrict__ hid,
                                            short* __restrict__ hbf, int n4h,
                                            const float* __restrict__ enc,
                                            short* __restrict__ ebf, int n4e) {
  __shared__ float t[32][33];
  int blk = blockIdx.x;
  if (blk < 6144) {
    int j = blk >> 10;
    int r = blk & 1023;
    int cb = (r & 31) * 32, rb = (r >> 5) * 32;
    const float* W = a.W[j];
    short* dst = wt + (size_t)j * (HDIM * HDIM);
    int tx = threadIdx.x & 31, ty = threadIdx.x >> 5;
#pragma unroll
    for (int rr = 0; rr < 4; ++rr)
      t[ty + rr * 8][tx] = W[(size_t)(rb + ty + rr * 8) * HDIM + cb + tx];
    __syncthreads();
#pragma unroll
    for (int rr = 0; rr < 4; ++rr)
      dst[(size_t)(cb + ty + rr * 8) * HDIM + rb + tx] = f2bf(t[tx][ty + rr * 8]);
  } else {
    int i = (blk - 6144) * 256 + threadIdx.x;
    const float* s;
    short* d;
    int j;
    if (i < n4h) { s = hid; d = hbf; j = i; }
    else { j = i - n4h; if (j >= n4e) return; s = enc; d = ebf; }
    f4v v = ((const f4v*)s)[j];
    s4v o;
#pragma unroll
    for (int k = 0; k < 4; ++k) o[k] = f2bf(v[k]);
    ((s4v*)d)[j] = o;
  }
}

// ---- kernel 3: projection GEMM (round-7/12 best: 75.6us) — FROZEN ----------
struct ProjArgs {
  const short* X[6];
  const short* Wt[6];
  const float* bias[6];
  short* out[6];
  int M[6];
  int tshift[6];
  int mode[6];
  float scale[6];
};

__global__ __launch_bounds__(256) void proj_gemm(ProjArgs a) {
  int job = blockIdx.z;
  int M = a.M[job];
  int by = blockIdx.y;
  if (by * 128 >= M) return;
  int bx = blockIdx.x;
  const short* X = a.X[job];
  const short* W = a.Wt[job];

  __shared__ __align__(16) char Lds[65536];   // 4 bufs x (A 8K | B 8K)

  int tid = threadIdx.x, lane = tid & 63, wave = tid >> 6;
  int wr = wave >> 1, wc = wave & 1;
  int l15 = lane & 15, g4 = lane >> 4;

  f32x4 acc[4][4];
#pragma unroll
  for (int m = 0; m < 4; ++m)
#pragma unroll
    for (int n = 0; n < 4; ++n)
#pragma unroll
      for (int r = 0; r < 4; ++r) acc[m][n][r] = 0.0f;

  int arow = by * 128, brow = bx * 128;
  const int crow = lane >> 2;
  const int sgrp = (lane & 3) ^ ((lane >> 2) & 3) ^ (lane >> 4);
  const int rsw = (lane & 3) ^ (l15 >> 2);

  const char* Xb = (const char*)X;
  const char* Wb = (const char*)W;
  const size_t sac0 = ((size_t)(arow + 32 * wave + crow) * HDIM + sgrp * 8) * 2;
  const size_t sac1 = sac0 + (size_t)16 * HDIM * 2;
  const size_t sbc0 = ((size_t)(brow + 32 * wave + crow) * HDIM + sgrp * 8) * 2;
  const size_t sbc1 = sbc0 + (size_t)16 * HDIM * 2;
  const int ldA0 = wave * 2048, ldA1 = ldA0 + 1024;
  const int ldB0 = 8192 + ldA0, ldB1 = ldB0 + 1024;

  const int aoff = wr * 4096 + l15 * 64 + ((g4 ^ rsw) << 4);
  const int boff = 8192 + wc * 4096 + l15 * 64 + ((g4 ^ rsw) << 4);

#define STG_A(SBO, SKT)                                                  \
  do {                                                                   \
    gload_lds16(Xb + sac0 + (size_t)(SKT) * 64, Lds + (SBO) + ldA0);     \
    gload_lds16(Xb + sac1 + (size_t)(SKT) * 64, Lds + (SBO) + ldA1);     \
  } while (0)
#define STG_B(SBO, SKT)                                                  \
  do {                                                                   \
    gload_lds16(Wb + sbc0 + (size_t)(SKT) * 64, Lds + (SBO) + ldB0);     \
    gload_lds16(Wb + sbc1 + (size_t)(SKT) * 64, Lds + (SBO) + ldB1);     \
  } while (0)

  STG_A(0, 0);     STG_B(0, 0);
  STG_A(16384, 1); STG_B(16384, 1);
  STG_A(32768, 2); STG_B(32768, 2);
  asm volatile("s_waitcnt vmcnt(4)" ::: "memory");
  __builtin_amdgcn_s_barrier();
  asm volatile("" ::: "memory");

  bf16x8 xa0, xa1, xb0, xb1, xb2, xb3;
  bf16x8 ya0, ya1, yb0, yb1, yb2, yb3;

  xa0 = *(const bf16x8*)(Lds + 0 * 1024 + aoff);
  xa1 = *(const bf16x8*)(Lds + 1 * 1024 + aoff);
  xb0 = *(const bf16x8*)(Lds + 0 * 1024 + boff);
  xb1 = *(const bf16x8*)(Lds + 1 * 1024 + boff);
  xb2 = *(const bf16x8*)(Lds + 2 * 1024 + boff);
  xb3 = *(const bf16x8*)(Lds + 3 * 1024 + boff);

#define GSTEP_I(BO, BON, CA0, CA1, CB0, CB1, CB2, CB3, NA0, NA1, NB0, NB1,    \
                NB2, NB3, DO_STG, SBO, SKT, DO_NEXT, VMASM, DO_BAR)           \
  do {                                                                        \
    bf16x8 q2 = *(const bf16x8*)(Lds + (BO) + 2 * 1024 + aoff);               \
    bf16x8 q3 = *(const bf16x8*)(Lds + (BO) + 3 * 1024 + aoff);               \
    if (DO_STG) STG_A(SBO, SKT);                                              \
    __builtin_amdgcn_s_setprio(1);                                            \
    acc[0][0] = MF(CA0, CB0, acc[0][0]);                                      \
    acc[0][1] = MF(CA0, CB1, acc[0][1]);                                      \
    acc[0][2] = MF(CA0, CB2, acc[0][2]);                                      \
    acc[0][3] = MF(CA0, CB3, acc[0][3]);                                      \
    acc[1][0] = MF(CA1, CB0, acc[1][0]);                                      \
    acc[1][1] = MF(CA1, CB1, acc[1][1]);                                      \
    acc[1][2] = MF(CA1, CB2, acc[1][2]);                                      \
    acc[1][3] = MF(CA1, CB3, acc[1][3]);                                      \
    __builtin_amdgcn_s_setprio(0);                                            \
    if (DO_NEXT) {                                                            \
      NA0 = *(const bf16x8*)(Lds + (BON) + 0 * 1024 + aoff);                  \
      NA1 = *(const bf16x8*)(Lds + (BON) + 1 * 1024 + aoff);                  \
      NB0 = *(const bf16x8*)(Lds + (BON) + 0 * 1024 + boff);                  \
      NB1 = *(const bf16x8*)(Lds + (BON) + 1 * 1024 + boff);                  \
      NB2 = *(const bf16x8*)(Lds + (BON) + 2 * 1024 + boff);                  \
      NB3 = *(const bf16x8*)(Lds + (BON) + 3 * 1024 + boff);                  \
    }                                                                         \
    if (DO_STG) STG_B(SBO, SKT);                                              \
    __builtin_amdgcn_s_setprio(1);                                            \
    acc[2][0] = MF(q2, CB0, acc[2][0]);                                       \
    acc[2][1] = MF(q2, CB1, acc[2][1]);                                       \
    acc[2][2] = MF(q2, CB2, acc[2][2]);                                       \
    acc[2][3] = MF(q2, CB3, acc[2][3]);                                       \
    acc[3][0] = MF(q3, CB0, acc[3][0]);                                       \
    acc[3][1] = MF(q3, CB1, acc[3][1]);                                       \
    acc[3][2] = MF(q3, CB2, acc[3][2]);                                       \
    acc[3][3] = MF(q3, CB3, acc[3][3]);                                       \
    __builtin_amdgcn_s_setprio(0);                                            \
    asm volatile(VMASM ::: "memory");                                         \
    if (DO_BAR) {                                                             \
      __builtin_amdgcn_s_barrier();                                           \
      asm volatile("" ::: "memory");                                          \
    }                                                                         \
  } while (0)
#define GSTEP(...) GSTEP_I(__VA_ARGS__)

#define XSET xa0, xa1, xb0, xb1, xb2, xb3
#define YSET ya0, ya1, yb0, yb1, yb2, yb3

#pragma unroll 1
  for (int it = 0; it < 7; ++it) {
    int t0 = it * 4;
    GSTEP(0,     16384, XSET, YSET, 1, 49152, t0 + 3, 1, "s_waitcnt vmcnt(4)", 1);
    GSTEP(16384, 32768, YSET, XSET, 1, 0,     t0 + 4, 1, "s_waitcnt vmcnt(4)", 1);
    GSTEP(32768, 49152, XSET, YSET, 1, 16384, t0 + 5, 1, "s_waitcnt vmcnt(4)", 1);
    GSTEP(49152, 0,     YSET, XSET, 1, 32768, t0 + 6, 1, "s_waitcnt vmcnt(4)", 1);
  }
  GSTEP(0,     16384, XSET, YSET, 1, 49152, 31, 1, "s_waitcnt vmcnt(4)", 1);
  GSTEP(16384, 32768, YSET, XSET, 0, 0, 0,      1, "s_waitcnt vmcnt(0)", 1);
  GSTEP(32768, 49152, XSET, YSET, 0, 0, 0,      1, "s_nop 0", 1);
  GSTEP(49152, 0,     YSET, XSET, 0, 0, 0,      0, "s_nop 0", 0);

#undef GSTEP
#undef GSTEP_I
#undef XSET
#undef YSET
#undef STG_A
#undef STG_B

  const float* bias = a.bias[job];
  short* out = a.out[job];
  int tshift = a.tshift[job], tmask = (1 << tshift) - 1, mode = a.mode[job];
  float scl = a.scale[job];
#pragma unroll
  for (int m = 0; m < 4; ++m) {
    int rowb = arow + wr * 64 + m * 16 + (g4 << 2);
#pragma unroll
    for (int n = 0; n < 4; ++n) {
      int col = brow + wc * 64 + n * 16 + l15;
      float bv = bias[col];
      int head = col >> 6, d = col & 63;
#pragma unroll
      for (int r = 0; r < 4; ++r) {
        int row = rowb + r;
        int bb = row >> tshift, tk = row & tmask;
        float val = (acc[m][n][r] + bv) * scl;
        size_t idx;
        if (mode == 0)
          idx = ((((size_t)bb * NHEAD + head) << tshift) + tk) * 64 + d;
        else
          idx = ((((size_t)bb * NHEAD + head) * 64 + d) << tshift) + tk;
        out[idx] = f2bf(val);
      }
    }
  }
}

// ---- kernel 4: swapped-QK^T 32x32 flash attention --------------------------
// Round 13: 2-wave blocks (QBLK=64), grid 1024 = 4 barrier-domains/CU (was 2)
// to hide softmax dependency chains; tree max/sum reductions (depth 5 vs 31).
__global__ __launch_bounds__(128, 2) void attn32(
    const short* __restrict__ qall, const short* __restrict__ kall,
    const short* __restrict__ vTall, const short* __restrict__ kqall,
    const short* __restrict__ kkall, const short* __restrict__ kvTall,
    const float* __restrict__ amask, const float* __restrict__ emask,
    float* __restrict__ out) {
  __shared__ char KT[2][8192];
  __shared__ char VT[2][8192];
  __shared__ float red[2][32];

  int lid = blockIdx.x;
  int id = (lid & 7) * 128 + (lid >> 3);  // 1024 = 8 XCD x 128; bh-contiguous
  int bh = id >> 4, qb = id & 15;
  int b = bh >> 4, h = bh & 15;
  int lane = threadIdx.x & 63, wave = threadIdx.x >> 6;   // wave 0..1
  int l31 = lane & 31, hi = lane >> 5, x7 = l31 & 7;
  int qrow0 = qb * 64 + wave * 32;

  bf16x8 qcur[4];
  {
    const short* qp = qall + ((size_t)bh * SEQ + qrow0 + l31) * 64;
#pragma unroll
    for (int i = 0; i < 4; ++i)
      qcur[i] = *(const bf16x8*)(qp + i * 16 + hi * 8);
  }

  const char* kb0 = (const char*)(kall + (size_t)bh * SEQ * 64);
  const char* vb0 = (const char*)(vTall + (size_t)bh * 64 * SEQ);
  const char* kb1 = (const char*)(kkall + (size_t)bh * KENC * 64);
  const char* vb1 = (const char*)(kvTall + (size_t)bh * 64 * KENC);
  const float* mpc = amask + (size_t)b * SEQ;

  auto STAGE = [&](int pb, const char* kb, const char* vb, size_t vrowb, int kt) {
    int t0 = threadIdx.x;
#pragma unroll
    for (int c = 0; c < 4; ++c) {
      int idx = c * 128 + t0;           // 512 16B chunks each for K and V
      int row = idx >> 3, phys = idx & 7;
      int lg = phys ^ (row & 7);
      gload_lds16(kb + ((size_t)(kt * 64 + row)) * 128 + lg * 16,
                  KT[pb] + idx * 16);
      gload_lds16(vb + (size_t)row * vrowb + (size_t)kt * 128 + lg * 16,
                  VT[pb] + idx * 16);
    }
  };

  STAGE(0, kb0, vb0, SEQ * 2, 0);

  f32x16 ctx0, ctx1, c10, c11;
#pragma unroll
  for (int r = 0; r < 16; ++r) { ctx0[r] = 0.f; ctx1[r] = 0.f; c10[r] = 0.f; c11[r] = 0.f; }
  float mr = -1e30f, lr = 0.f;

#pragma unroll 1
  for (int t = 0; t < 24; ++t) {
    int p = t & 1;
    __syncthreads();
    if (t < 23) {
      int tn = t + 1;
      if (tn >= 16) STAGE(p ^ 1, kb1, vb1, KENC * 2, tn - 16);
      else          STAGE(p ^ 1, kb0, vb0, SEQ * 2, tn);
    }
    if (t == 16) {
      if (!hi) red[wave][l31] = lr;
      asm volatile("s_waitcnt lgkmcnt(0)" ::: "memory");
#pragma unroll
      for (int r2 = 0; r2 < 4; ++r2) {
        f4v lv = *(const f4v*)(&red[wave][r2 * 8 + 4 * hi]);
#pragma unroll
        for (int j2 = 0; j2 < 4; ++j2) {
          float li = __builtin_amdgcn_rcpf(lv[j2]);
          int r = r2 * 4 + j2;
          c10[r] = ctx0[r] * li;  ctx0[r] = 0.f;
          c11[r] = ctx1[r] * li;  ctx1[r] = 0.f;
        }
      }
      mr = -1e30f; lr = 0.f;
      const short* kqp = kqall + ((size_t)bh * SEQ + qrow0 + l31) * 64;
#pragma unroll
      for (int i = 0; i < 4; ++i)
        qcur[i] = *(const bf16x8*)(kqp + i * 16 + hi * 8);
      mpc = emask + (size_t)b * KENC;
    }
    int kt = (t >= 16) ? t - 16 : t;
    const char* Kp = KT[p];
    const char* Vp = VT[p];

    f32x16 s0, s1;
#pragma unroll
    for (int r = 0; r < 16; ++r) { s0[r] = 0.f; s1[r] = 0.f; }
    __builtin_amdgcn_s_setprio(1);
#pragma unroll
    for (int i = 0; i < 4; ++i) {
      bf16x8 kf = *(const bf16x8*)(Kp + (l31)*128 + (((2 * i + hi) ^ x7) << 4));
      s0 = __builtin_amdgcn_mfma_f32_32x32x16_bf16(kf, qcur[i], s0, 0, 0, 0);
    }
#pragma unroll
    for (int i = 0; i < 4; ++i) {
      bf16x8 kf = *(const bf16x8*)(Kp + (32 + l31) * 128 + (((2 * i + hi) ^ x7) << 4));
      s1 = __builtin_amdgcn_mfma_f32_32x32x16_bf16(kf, qcur[i], s1, 0, 0, 0);
    }
    __builtin_amdgcn_s_setprio(0);

    const float* mp = mpc + kt * 64;
#pragma unroll
    for (int r2 = 0; r2 < 4; ++r2) {
      f4v ma = *(const f4v*)(mp + r2 * 8 + 4 * hi);
      f4v mb = *(const f4v*)(mp + 32 + r2 * 8 + 4 * hi);
#pragma unroll
      for (int j2 = 0; j2 < 4; ++j2) {
        s0[r2 * 4 + j2] = fmaf(ma[j2], LOG2E, s0[r2 * 4 + j2]);
        s1[r2 * 4 + j2] = fmaf(mb[j2], LOG2E, s1[r2 * 4 + j2]);
      }
    }

    float mx = fmaxf(tmax16(s0), tmax16(s1));
    mx = fmaxf(mx, __int_as_float(__shfl_xor(__float_as_int(mx), 32)));

    if (!__all(mx <= mr + 12.f)) {
      float mn = fmaxf(mr, mx);
      float scl = __builtin_amdgcn_exp2f(mr - mn);
      mr = mn; lr *= scl;
      if (!hi) red[wave][l31] = scl;
      asm volatile("s_waitcnt lgkmcnt(0)" ::: "memory");
#pragma unroll
      for (int r2 = 0; r2 < 4; ++r2) {
        f4v sv = *(const f4v*)(&red[wave][r2 * 8 + 4 * hi]);
#pragma unroll
        for (int j2 = 0; j2 < 4; ++j2) {
          ctx0[r2 * 4 + j2] *= sv[j2];
          ctx1[r2 * 4 + j2] *= sv[j2];
        }
      }
    }

#pragma unroll
    for (int r = 0; r < 16; ++r) s0[r] = __builtin_amdgcn_exp2f(s0[r] - mr);
#pragma unroll
    for (int r = 0; r < 16; ++r) s1[r] = __builtin_amdgcn_exp2f(s1[r] - mr);
    float rs = tsum16(s0) + tsum16(s1);
    rs += __int_as_float(__shfl_xor(__float_as_int(rs), 32));
    lr += rs;

#pragma unroll
    for (int s = 0; s < 2; ++s) {
      const f32x16& sv = s ? s1 : s0;
      unsigned W[8];
#pragma unroll
      for (int r2 = 0; r2 < 4; ++r2) {
        asm("v_cvt_pk_bf16_f32 %0, %1, %2"
            : "=v"(W[r2 * 2]) : "v"(sv[r2 * 4 + 0]), "v"(sv[r2 * 4 + 1]));
        asm("v_cvt_pk_bf16_f32 %0, %1, %2"
            : "=v"(W[r2 * 2 + 1]) : "v"(sv[r2 * 4 + 2]), "v"(sv[r2 * 4 + 3]));
      }
#pragma unroll
      for (int jr = 0; jr < 2; ++jr) {
        unsigned sendA = hi ? W[(2 * jr) * 2]     : W[(2 * jr + 1) * 2];
        unsigned sendB = hi ? W[(2 * jr) * 2 + 1] : W[(2 * jr + 1) * 2 + 1];
        unsigned rA = (unsigned)__shfl_xor((int)sendA, 32);
        unsigned rB = (unsigned)__shfl_xor((int)sendB, 32);
        union { unsigned u[4]; bf16x8 v; } pa;
        if (!hi) { pa.u[0] = W[2 * jr * 2]; pa.u[1] = W[2 * jr * 2 + 1];
                   pa.u[2] = rA;            pa.u[3] = rB; }
        else     { pa.u[0] = rA;            pa.u[1] = rB;
                   pa.u[2] = W[(2 * jr + 1) * 2]; pa.u[3] = W[(2 * jr + 1) * 2 + 1]; }
        int j = s * 2 + jr;
        __builtin_amdgcn_s_setprio(1);
        bf16x8 vf0 = *(const bf16x8*)(Vp + (l31)*128 + (((2 * j + hi) ^ x7) << 4));
        ctx0 = __builtin_amdgcn_mfma_f32_32x32x16_bf16(pa.v, vf0, ctx0, 0, 0, 0);
        bf16x8 vf1 = *(const bf16x8*)(Vp + (32 + l31) * 128 + (((2 * j + hi) ^ x7) << 4));
        ctx1 = __builtin_amdgcn_mfma_f32_32x32x16_bf16(pa.v, vf1, ctx1, 0, 0, 0);
        __builtin_amdgcn_s_setprio(0);
      }
    }
  }

  if (!hi) red[wave][l31] = lr;
  asm volatile("s_waitcnt lgkmcnt(0)" ::: "memory");
  float* op = out + ((size_t)b * SEQ) * HDIM + h * 64 + l31;
#pragma unroll
  for (int r2 = 0; r2 < 4; ++r2) {
    f4v lv = *(const f4v*)(&red[wave][r2 * 8 + 4 * hi]);
#pragma unroll
    for (int j2 = 0; j2 < 4; ++j2) {
      float li = __builtin_amdgcn_rcpf(lv[j2]);
      int s = qrow0 + r2 * 8 + 4 * hi + j2;
      int r = r2 * 4 + j2;
      op[(size_t)s * HDIM]      = 0.5f * (c10[r] + ctx0[r] * li);
      op[(size_t)s * HDIM + 32] = 0.5f * (c11[r] + ctx1[r] * li);
    }
  }
}

// ---- host launcher ---------------------------------------------------------
extern "C" void kernel_launch(void* const* d_in, const int* in_sizes, int n_in,
                              void* d_out, int out_size, void* d_ws, size_t ws_size,
                              hipStream_t stream) {
  const float* hid = (const float*)d_in[0];
  const float* enc = (const float*)d_in[1];
  const float* amask = (const float*)d_in[2];
  const float* emask = (const float*)d_in[3];

  char* ws = (char*)d_ws;
  short* hbf = (short*)(ws);                        // 8 MB  [B*S,H] bf16
  short* ebf = (short*)(ws + (8u << 20));           // 4 MB  [B*K,H]
  short* wt = (short*)(ws + (12u << 20));           // 12 MB 6x [n][k]
  short* qo = (short*)(ws + (24u << 20));           // 8 MB  [B,NH,S,HD]
  short* ko = (short*)(ws + (32u << 20));           // 8 MB
  short* vT = (short*)(ws + (40u << 20));           // 8 MB  [B,NH,HD,S]
  short* kqo = (short*)(ws + (48u << 20));          // 8 MB
  short* kko = (short*)(ws + (56u << 20));          // 4 MB  [B,NH,K,HD]
  short* kvT = (short*)(ws + (60u << 20));          // 4 MB  [B,NH,HD,K]

  PrepArgs wa;
  for (int j = 0; j < 6; ++j) wa.W[j] = (const float*)d_in[4 + 2 * j];
  prep<<<12288, 256, 0, stream>>>(wa, wt, hid, hbf, (BATCH * SEQ * HDIM) / 4,
                                  enc, ebf, (BATCH * KENC * HDIM) / 4);

  ProjArgs pa;
  const short* Xs[6] = {hbf, hbf, hbf, hbf, ebf, ebf};
  short* outs[6] = {qo, ko, vT, kqo, kko, kvT};
  const int Ms[6] = {4096, 4096, 4096, 4096, 2048, 2048};
  const int tsh[6] = {10, 10, 10, 10, 9, 9};
  const int md[6] = {0, 0, 1, 0, 0, 1};
  const float qscale = 0.125f * LOG2E;
  const float scl[6] = {qscale, 1.f, 1.f, qscale, 1.f, 1.f};
  for (int j = 0; j < 6; ++j) {
    pa.X[j] = Xs[j];
    pa.Wt[j] = wt + (size_t)j * (HDIM * HDIM);
    pa.bias[j] = (const float*)d_in[5 + 2 * j];
    pa.out[j] = outs[j];
    pa.M[j] = Ms[j];
    pa.tshift[j] = tsh[j];
    pa.mode[j] = md[j];
    pa.scale[j] = scl[j];
  }
  proj_gemm<<<dim3(8, 32, 6), 256, 0, stream>>>(pa);

  attn32<<<1024, 128, 0, stream>>>(qo, ko, vT, kqo, kko, kvT, amask, emask,
                                   (float*)d_out);
}